// Round 6
// baseline (863.239 us; speedup 1.0000x reference)
//
#include <hip/hip_runtime.h>

// TreeLstmDecoder: B=64 trees, K=4, D=6, V=600, L=256, N_PER=1365, N=87360.
// 13-launch schedule (sibling chain and parent chain are independent; each
// launch merges one step of each via block-index branching):
//  L1  k_pack
//  L2  s0 (21824) || zdual (root hpred + gatesP)
//  L3  sibdual1 || plstm0
//  L4  siblstm1 || pdual1 (PPA d1 + gatesP)
//  L5  sibdual2 || plstm1
//  L6  siblstm2 || pdual2 (PPA d2 + gatesP)
//  L7  sibdual3 (UPROJ only) || plstm2
//  L8  pdual3  (fused HPRED epilogue + gatesP)
//  L9  plstm3 || assemble (rows 0..319, depths 1-2)
//  L10 pdual4  (fused HPRED epilogue + gatesP)
//  L11 plstm4
//  L12 pdual5  (fused HPRED epilogue, no gates)
//  L13 k_mm_tail (87360x602x256 GEMM + log-softmax, register-resident,
//                 NONTEMPORAL out stores so B stays L2-resident)
// All GEMMs: C = A*B^T, bf16 operands, fp32 MFMA accumulate.

typedef unsigned short u16;
typedef short bf16x8 __attribute__((ext_vector_type(8)));
typedef float f32x4 __attribute__((ext_vector_type(4)));

#define NPER 1365
#define VDIM 600
#define VD2  602

#define MODE_PPA   0
#define MODE_UPROJ 1
#define MODE_ROOT  2
#define MODE_EPI   3

__device__ __forceinline__ float b2f(u16 h) {
  union { unsigned u; float f; } v; v.u = ((unsigned)h) << 16; return v.f;
}
__device__ __forceinline__ u16 f2bf(float f) {
  union { float f; unsigned u; } v; v.f = f;
  unsigned r = v.u + 0x7fff + ((v.u >> 16) & 1);
  return (u16)(r >> 16);
}
__device__ __forceinline__ float fsigm(float x) {
  return __fdividef(1.f, 1.f + __expf(-x));
}
__device__ __forceinline__ float ftanh(float x) {
  float e = __expf(-2.f * fabsf(x));
  float r = __fdividef(1.f - e, 1.f + e);
  return x < 0.f ? -r : r;
}

// chain-row ladder: r -> (off, pcs, start) for depths 1..5
__device__ __forceinline__ void ladder(int r, int& off, int& pcs, int& start) {
  if (r < 64)        { off = 0;    pcs = 0; start = 1;   }
  else if (r < 320)  { off = 64;   pcs = 2; start = 5;   }
  else if (r < 1344) { off = 320;  pcs = 4; start = 21;  }
  else if (r < 5440) { off = 1344; pcs = 6; start = 85;  }
  else               { off = 5440; pcs = 8; start = 341; }
}

// ---------------- pack kernel -----------------------------------------------
__global__ void k_pack(
    const float* __restrict__ Upar, const float* __restrict__ Whhp,
    const float* __restrict__ Usib, const float* __restrict__ Whhs,
    const float* __restrict__ z, const float* __restrict__ Wihp,
    const float* __restrict__ Wihs, const float* __restrict__ Wlab,
    const float* __restrict__ Wd, const float* __restrict__ Ww,
    const float* __restrict__ blab, const float* __restrict__ bd,
    const float* __restrict__ bw, const float* __restrict__ bihp,
    const float* __restrict__ bhhp, const float* __restrict__ bihs,
    const float* __restrict__ bhhs,
    u16* __restrict__ UPWHHP, u16* __restrict__ USWHHS, u16* __restrict__ ZBF,
    u16* __restrict__ WIHPT, u16* __restrict__ WIHST, u16* __restrict__ WEXT,
    float* __restrict__ BE, float* __restrict__ BP, float* __restrict__ BS) {
  int i = blockIdx.x * 256 + threadIdx.x;
  if (i < 327680) {
    int r = i >> 8, c = i & 255;
    UPWHHP[i] = f2bf(r < 256 ? Upar[(r << 8) | c] : Whhp[((r - 256) << 8) | c]);
    return;
  }
  i -= 327680;
  if (i < 327680) {
    int r = i >> 8, c = i & 255;
    USWHHS[i] = f2bf(r < 256 ? Usib[(r << 8) | c] : Whhs[((r - 256) << 8) | c]);
    return;
  }
  i -= 327680;
  if (i < 16384) { ZBF[i] = f2bf(z[i]); return; }
  i -= 16384;
  if (i < 614400) {  // W_ih_p [1024,600] -> [600,1024]; coalesced writes
    int r = i >> 10, c = i & 1023;
    WIHPT[i] = f2bf(Wihp[c * VDIM + r]); return;
  }
  i -= 614400;
  if (i < 614400) {
    int r = i >> 10, c = i & 1023;
    WIHST[i] = f2bf(Wihs[c * VDIM + r]); return;
  }
  i -= 614400;
  if (i < VD2 * 256) {
    int r = i >> 8, c = i & 255;
    float v = (r < VDIM) ? Wlab[r * 256 + c] : ((r == VDIM) ? Wd[c] : Ww[c]);
    WEXT[i] = f2bf(v); return;
  }
  i -= VD2 * 256;
  if (i < VD2) { BE[i] = (i < VDIM) ? blab[i] : ((i == VDIM) ? bd[0] : bw[0]); return; }
  i -= VD2;
  if (i < 1024) { BP[i] = bihp[i] + bhhp[i]; return; }
  i -= 1024;
  if (i < 1024) { BS[i] = bihs[i] + bhhs[i]; return; }
}

// ---------------- dual GEMM device fn: C = A*B^T, B=[1280,256] concat -------
// n0>=256 tiles -> gates. n0<256 tiles by mode:
//  MODE_PPA  : ppa[(ppoff+row)*256+col] = bf16(acc)
//  MODE_UPROJ: uproj[row*256+col] = acc (fp32, nontemporal)
//  MODE_ROOT : hpred[row*NPER*256+col] = bf16(tanh(acc))
//  MODE_EPI  : node base = (row>>lsb)*NPER + startd + 4*(row&(2^lsb-1));
//              hpred rows s=0..3 = tanh(acc [+ U_s[(ppoff+row)*256+col]])
__device__ __forceinline__ void dev_dual(
    int tile, int nx, const u16* __restrict__ A, const u16* __restrict__ B,
    int M, int mode, u16* __restrict__ ppa, int ppoff,
    float* __restrict__ uproj, u16* __restrict__ gates,
    u16* __restrict__ hpred, const float* __restrict__ U1,
    const float* __restrict__ U2, const float* __restrict__ U3,
    int lsb, int startd) {
  static __shared__ __align__(16) u16 As[128 * 40];
  static __shared__ __align__(16) u16 Bs[128 * 40];
  const int m0 = (tile % nx) * 128, n0 = (tile / nx) * 128;
  const int tid = threadIdx.x;
  const int wave = tid >> 6, lane = tid & 63;
  const int quad = lane >> 4, lr = lane & 15;
  const int wm = (wave >> 1) * 64, wn = (wave & 1) * 64;
  const int srow = tid >> 2;
  const int sch = (tid & 3) << 3;

  f32x4 acc[4][4] = {};
  for (int t = 0; t < 8; ++t) {
    const int kk = t * 32;
    bf16x8 a0 = *(const bf16x8*)(A + (size_t)(m0 + srow) * 256 + kk + sch);
    bf16x8 a1 = *(const bf16x8*)(A + (size_t)(m0 + srow + 64) * 256 + kk + sch);
    bf16x8 b0 = *(const bf16x8*)(B + (size_t)(n0 + srow) * 256 + kk + sch);
    bf16x8 b1 = *(const bf16x8*)(B + (size_t)(n0 + srow + 64) * 256 + kk + sch);
    __syncthreads();
    *(bf16x8*)&As[srow * 40 + sch] = a0;
    *(bf16x8*)&As[(srow + 64) * 40 + sch] = a1;
    *(bf16x8*)&Bs[srow * 40 + sch] = b0;
    *(bf16x8*)&Bs[(srow + 64) * 40 + sch] = b1;
    __syncthreads();
    bf16x8 af[4], bfr[4];
#pragma unroll
    for (int tm = 0; tm < 4; ++tm)
      af[tm] = *(const bf16x8*)&As[(wm + tm * 16 + lr) * 40 + quad * 8];
#pragma unroll
    for (int tn = 0; tn < 4; ++tn)
      bfr[tn] = *(const bf16x8*)&Bs[(wn + tn * 16 + lr) * 40 + quad * 8];
#pragma unroll
    for (int tm = 0; tm < 4; ++tm)
#pragma unroll
      for (int tn = 0; tn < 4; ++tn)
        acc[tm][tn] = __builtin_amdgcn_mfma_f32_16x16x32_bf16(
            af[tm], bfr[tn], acc[tm][tn], 0, 0, 0);
  }

  const bool isg = (n0 >= 256);
#pragma unroll
  for (int tn = 0; tn < 4; ++tn) {
    int col = n0 + wn + tn * 16 + lr;
#pragma unroll
    for (int tm = 0; tm < 4; ++tm) {
#pragma unroll
      for (int r = 0; r < 4; ++r) {
        int row = m0 + wm + tm * 16 + quad * 4 + r;
        if (row >= M) continue;
        float v = acc[tm][tn][r];
        if (isg) {
          gates[(size_t)row * 1024 + (col - 256)] = f2bf(v);
        } else if (mode == MODE_PPA) {
          ppa[(size_t)(ppoff + row) * 256 + col] = f2bf(v);
        } else if (mode == MODE_UPROJ) {
          __builtin_nontemporal_store(v, &uproj[(size_t)row * 256 + col]);
        } else if (mode == MODE_ROOT) {
          hpred[(size_t)row * NPER * 256 + col] = f2bf(ftanh(v));
        } else {  // MODE_EPI
          int t2 = row >> lsb, j = row & ((1 << lsb) - 1);
          size_t bb = ((size_t)(t2 * NPER + startd + 4 * j)) * 256 + col;
          size_t ro = (size_t)(ppoff + row) * 256 + col;
          hpred[bb]       = f2bf(ftanh(v));
          hpred[bb + 256] = f2bf(ftanh(v + U1[ro]));
          hpred[bb + 512] = f2bf(ftanh(v + U2[ro]));
          hpred[bb + 768] = f2bf(ftanh(v + U3[ro]));
        }
      }
    }
  }
}

// ---------------- LSTM elementwise device fns -------------------------------

__device__ __forceinline__ void dev_s0(int r, const u16* __restrict__ wihT,
    const float* __restrict__ bias, const int* __restrict__ feat,
    u16* __restrict__ h, u16* __restrict__ c) {
  int u = threadIdx.x;
  int off, pcs, start; ladder(r, off, pcs, start);
  int lg = r - off;
  int t = lg >> pcs, j = lg & ((1 << pcs) - 1);
  int lab = feat[t * NPER + start + 4 * j];
  const u16* wr = wihT + lab * 1024;
  float gi = b2f(wr[u])       + bias[u];
  float gg = b2f(wr[512 + u]) + bias[512 + u];
  float go = b2f(wr[768 + u]) + bias[768 + u];
  float cn = fsigm(gi) * ftanh(gg);
  float hn = fsigm(go) * ftanh(cn);
  h[(size_t)r * 256 + u] = f2bf(hn);
  c[(size_t)r * 256 + u] = f2bf(cn);
}

__device__ __forceinline__ void dev_lstm_sib(int r, int k,
    const u16* __restrict__ gates, const u16* __restrict__ wihT,
    const float* __restrict__ bias, const u16* __restrict__ c_in,
    const int* __restrict__ feat, u16* __restrict__ h, u16* __restrict__ c) {
  int u = threadIdx.x;
  int off, pcs, start; ladder(r, off, pcs, start);
  int lg = r - off;
  int t = lg >> pcs, j = lg & ((1 << pcs) - 1);
  int lab = feat[t * NPER + start + 4 * j + k];
  const u16* wr = wihT + lab * 1024;
  const u16* gr = gates + (size_t)r * 1024;
  float gi = b2f(wr[u])       + bias[u]       + b2f(gr[u]);
  float gf = b2f(wr[256 + u]) + bias[256 + u] + b2f(gr[256 + u]);
  float gg = b2f(wr[512 + u]) + bias[512 + u] + b2f(gr[512 + u]);
  float go = b2f(wr[768 + u]) + bias[768 + u] + b2f(gr[768 + u]);
  float cv = b2f(c_in[(size_t)r * 256 + u]);
  float cn = fsigm(gf) * cv + fsigm(gi) * ftanh(gg);
  float hn = fsigm(go) * ftanh(cn);
  h[(size_t)r * 256 + u] = f2bf(hn);
  c[(size_t)r * 256 + u] = f2bf(cn);
}

__device__ __forceinline__ void dev_lstm_par(int g,
    const u16* __restrict__ gates, const u16* __restrict__ wihT,
    const float* __restrict__ bias, const u16* __restrict__ c_in,
    const int* __restrict__ feat, u16* __restrict__ h, u16* __restrict__ c,
    int lsbits, int start) {
  int u = threadIdx.x;
  int t = g >> lsbits, p = g & ((1 << lsbits) - 1);
  int pr = lsbits ? ((t << (lsbits - 2)) | (p >> 2)) : g;
  int lab = feat[t * NPER + start + p];
  const u16* wr = wihT + lab * 1024;
  const u16* gr = gates + (size_t)pr * 1024;
  float gi = b2f(wr[u])       + bias[u]       + b2f(gr[u]);
  float gf = b2f(wr[256 + u]) + bias[256 + u] + b2f(gr[256 + u]);
  float gg = b2f(wr[512 + u]) + bias[512 + u] + b2f(gr[512 + u]);
  float go = b2f(wr[768 + u]) + bias[768 + u] + b2f(gr[768 + u]);
  float cv = c_in ? b2f(c_in[(size_t)pr * 256 + u]) : 0.f;
  float cn = fsigm(gf) * cv + fsigm(gi) * ftanh(gg);
  float hn = fsigm(go) * ftanh(cn);
  h[(size_t)g * 256 + u] = f2bf(hn);
  c[(size_t)g * 256 + u] = f2bf(cn);
}

__device__ __forceinline__ void dev_assemble(int r,
    const u16* __restrict__ PPA, const float* __restrict__ U1,
    const float* __restrict__ U2, const float* __restrict__ U3,
    u16* __restrict__ HPRED) {
  int u = threadIdx.x;
  int off, pcs, start; ladder(r, off, pcs, start);
  int lg = r - off;
  int t = lg >> pcs, j = lg & ((1 << pcs) - 1);
  size_t base = ((size_t)(t * NPER + start + 4 * j)) * 256 + u;
  size_t ro = (size_t)r * 256 + u;
  float pp = b2f(PPA[ro]);
  HPRED[base]       = f2bf(ftanh(pp));
  HPRED[base + 256] = f2bf(ftanh(pp + U1[ro]));
  HPRED[base + 512] = f2bf(ftanh(pp + U2[ro]));
  HPRED[base + 768] = f2bf(ftanh(pp + U3[ro]));
}

// ---------------- merged launch kernels -------------------------------------

// L2: s0 (21824 blocks) || zdual (10 tiles, root hpred + gatesP)
__global__ __launch_bounds__(256) void k_s0_zdual(
    const u16* WIHST, const float* BS, const int* feat, u16* h, u16* c,
    const u16* ZBF, const u16* UPWHHP, u16* HPRED, u16* GATESP) {
  int b = blockIdx.x;
  if (b < 21824)
    dev_s0(b, WIHST, BS, feat, h, c);
  else
    dev_dual(b - 21824, 1, ZBF, UPWHHP, 64, MODE_ROOT, nullptr, 0, nullptr,
             GATESP, HPRED, nullptr, nullptr, nullptr, 0, 0);
}

// L3/L5/L7: sibdual (nSib tiles, UPROJ+gates) || plstm (nPar blocks)
__global__ __launch_bounds__(256) void k_sibdual_plstm(
    int nSib, int nx, const u16* HSAin, const u16* USWHHS,
    float* UPROJk, u16* GATES,
    const u16* GATESP, const u16* WIHPT, const float* BP, const u16* CPin,
    const int* feat, u16* HPout, u16* CPout, int lsbits, int startp) {
  int b = blockIdx.x;
  if (b < nSib)
    dev_dual(b, nx, HSAin, USWHHS, 21824, MODE_UPROJ, nullptr, 0, UPROJk,
             GATES, nullptr, nullptr, nullptr, nullptr, 0, 0);
  else
    dev_lstm_par(b - nSib, GATESP, WIHPT, BP, CPin, feat, HPout, CPout,
                 lsbits, startp);
}

// L4/L6: siblstm (21824 blocks) || pdual (PPA + gatesP)
__global__ __launch_bounds__(256) void k_siblstm_pdual(
    int kSib, const u16* GATES, const u16* WIHST, const float* BS,
    const u16* CSAin, const int* feat, u16* HSAout, u16* CSAout,
    int nx, const u16* HPin, const u16* UPWHHP, int Mpar,
    u16* PPA, int ppoff, u16* GATESP) {
  int b = blockIdx.x;
  if (b < 21824)
    dev_lstm_sib(b, kSib, GATES, WIHST, BS, CSAin, feat, HSAout, CSAout);
  else
    dev_dual(b - 21824, nx, HPin, UPWHHP, Mpar, MODE_PPA, PPA, ppoff, nullptr,
             GATESP, nullptr, nullptr, nullptr, nullptr, 0, 0);
}

// L8/L10/L12: pdual with fused HPRED epilogue (+ gatesP when ny=10)
__global__ __launch_bounds__(256) void k_pdual_epi(
    int nx, const u16* HPin, const u16* UPWHHP, int M, u16* GATESP,
    u16* HPRED, const float* U1, const float* U2, const float* U3,
    int ppoff, int lsb, int startd) {
  dev_dual(blockIdx.x, nx, HPin, UPWHHP, M, MODE_EPI, nullptr, ppoff, nullptr,
           GATESP, HPRED, U1, U2, U3, lsb, startd);
}

// L9: plstm3 (4096 blocks) || assemble (320 rows: depths 1-2)
__global__ __launch_bounds__(256) void k_plstm_asm(
    const u16* GATESP, const u16* WIHPT, const float* BP, const u16* CPin,
    const int* feat, u16* HPout, u16* CPout,
    const u16* PPA, const float* U1, const float* U2, const float* U3,
    u16* HPRED) {
  int b = blockIdx.x;
  if (b < 4096)
    dev_lstm_par(b, GATESP, WIHPT, BP, CPin, feat, HPout, CPout, 6, 21);
  else
    dev_assemble(b - 4096, PPA, U1, U2, U3, HPRED);
}

// L11: plstm4 standalone
__global__ __launch_bounds__(256) void k_plstm(
    const u16* GATESP, const u16* WIHPT, const float* BP, const u16* CPin,
    const int* feat, u16* HPout, u16* CPout, int lsbits, int start) {
  dev_lstm_par(blockIdx.x, GATESP, WIHPT, BP, CPin, feat, HPout, CPout,
               lsbits, start);
}

// ---------------- fused tail: logits GEMM + log-softmax ---------------------
__global__ __launch_bounds__(256, 2) void k_mm_tail(
    const u16* __restrict__ A, const u16* __restrict__ B,
    const float* __restrict__ bias, float* __restrict__ out) {
  __shared__ __align__(16) u16 As[32 * 264];
  __shared__ float smax[32][4], ssum[32][4], slz[32];
  const int m0 = blockIdx.x * 32;
  const int tid = threadIdx.x;
  const int wave = tid >> 6, lane = tid & 63;
  const int quad = lane >> 4, lr = lane & 15;
  const int c0 = wave * 160;

#pragma unroll
  for (int c = 0; c < 4; ++c) {
    int idx = c * 256 + tid;
    int row = idx >> 5, ch = (idx & 31) << 3;
    *(bf16x8*)&As[row * 264 + ch] =
        *(const bf16x8*)(A + (size_t)(m0 + row) * 256 + ch);
  }
  __syncthreads();

  f32x4 acc[2][10] = {};
#pragma unroll
  for (int t = 0; t < 8; ++t) {
    bf16x8 af[2], bfr[10];
#pragma unroll
    for (int tm = 0; tm < 2; ++tm)
      af[tm] = *(const bf16x8*)&As[(tm * 16 + lr) * 264 + t * 32 + quad * 8];
#pragma unroll
    for (int tn = 0; tn < 10; ++tn)
      bfr[tn] = *(const bf16x8*)(B + (size_t)(c0 + tn * 16 + lr) * 256 +
                                 t * 32 + quad * 8);
#pragma unroll
    for (int tm = 0; tm < 2; ++tm)
#pragma unroll
      for (int tn = 0; tn < 10; ++tn)
        acc[tm][tn] = __builtin_amdgcn_mfma_f32_16x16x32_bf16(
            af[tm], bfr[tn], acc[tm][tn], 0, 0, 0);
  }

  float bv[10]; bool val[10];
#pragma unroll
  for (int tn = 0; tn < 10; ++tn) {
    int col = c0 + tn * 16 + lr;
    val[tn] = (col < VDIM);
    bv[tn] = (col < VD2) ? bias[col] : 0.f;
  }

#pragma unroll
  for (int tm = 0; tm < 2; ++tm) {
#pragma unroll
    for (int r = 0; r < 4; ++r) {
      float mx = -1e30f;
#pragma unroll
      for (int tn = 0; tn < 10; ++tn)
        if (val[tn]) mx = fmaxf(mx, acc[tm][tn][r] + bv[tn]);
#pragma unroll
      for (int o = 1; o < 16; o <<= 1) mx = fmaxf(mx, __shfl_xor(mx, o, 64));
      if (lr == 0) smax[tm * 16 + quad * 4 + r][wave] = mx;
    }
  }
  __syncthreads();
#pragma unroll
  for (int tm = 0; tm < 2; ++tm) {
#pragma unroll
    for (int r = 0; r < 4; ++r) {
      int row = tm * 16 + quad * 4 + r;
      float fm = fmaxf(fmaxf(smax[row][0], smax[row][1]),
                       fmaxf(smax[row][2], smax[row][3]));
      float se = 0.f;
#pragma unroll
      for (int tn = 0; tn < 10; ++tn)
        if (val[tn]) se += __expf(acc[tm][tn][r] + bv[tn] - fm);
#pragma unroll
      for (int o = 1; o < 16; o <<= 1) se += __shfl_xor(se, o, 64);
      if (lr == 0) ssum[row][wave] = se;
    }
  }
  __syncthreads();
  if (tid < 32) {
    float fm = fmaxf(fmaxf(smax[tid][0], smax[tid][1]),
                     fmaxf(smax[tid][2], smax[tid][3]));
    slz[tid] = fm + __logf(ssum[tid][0] + ssum[tid][1] +
                           ssum[tid][2] + ssum[tid][3]);
  }
  __syncthreads();

#pragma unroll
  for (int tm = 0; tm < 2; ++tm) {
#pragma unroll
    for (int tn = 0; tn < 10; ++tn) {
      int col = c0 + tn * 16 + lr;
      if (col >= VD2) continue;
#pragma unroll
      for (int r = 0; r < 4; ++r) {
        int row = tm * 16 + quad * 4 + r;
        float v = acc[tm][tn][r] + bv[tn];
        float o = (col < VDIM) ? (v - slz[row]) : fsigm(v);
        __builtin_nontemporal_store(o, &out[(size_t)(m0 + row) * VD2 + col]);
      }
    }
  }
}

// ---------------- host ------------------------------------------------------

extern "C" void kernel_launch(void* const* d_in, const int* in_sizes, int n_in,
                              void* d_out, int out_size, void* d_ws, size_t ws_size,
                              hipStream_t stream) {
  const float* z    = (const float*)d_in[0];
  const int*   feat = (const int*)d_in[1];
  const float* Wihp = (const float*)d_in[2];
  const float* Whhp = (const float*)d_in[3];
  const float* bihp = (const float*)d_in[4];
  const float* bhhp = (const float*)d_in[5];
  const float* Wihs = (const float*)d_in[6];
  const float* Whhs = (const float*)d_in[7];
  const float* bihs = (const float*)d_in[8];
  const float* bhhs = (const float*)d_in[9];
  const float* Upar = (const float*)d_in[10];
  const float* Usib = (const float*)d_in[11];
  const float* Wlab = (const float*)d_in[12];
  const float* blab = (const float*)d_in[13];
  const float* Wd   = (const float*)d_in[14];
  const float* bd   = (const float*)d_in[15];
  const float* Ww   = (const float*)d_in[16];
  const float* bw   = (const float*)d_in[17];
  float* out = (float*)d_out;

  char* w = (char*)d_ws;
  auto alloc = [&](size_t bytes) {
    char* p = w; w += (bytes + 255) & ~(size_t)255; return p;
  };
  u16*   UPWHHP = (u16*)alloc((size_t)1280 * 256 * 2);
  u16*   USWHHS = (u16*)alloc((size_t)1280 * 256 * 2);
  u16*   ZBF    = (u16*)alloc((size_t)128 * 256 * 2);   // rows 64..127 pad
  u16*   WIHPT  = (u16*)alloc((size_t)VDIM * 1024 * 2);
  u16*   WIHST  = (u16*)alloc((size_t)VDIM * 1024 * 2);
  u16*   WEXT   = (u16*)alloc((size_t)640 * 256 * 2);   // rows 602..639 pad
  float* BE     = (float*)alloc(VD2 * 4);
  float* BP     = (float*)alloc(1024 * 4);
  float* BS     = (float*)alloc(1024 * 4);
  const size_t CR = 21888;                              // 171*128 chain rows
  u16*   HSA[3], *CSA[3];
  for (int k = 0; k < 3; ++k) {
    HSA[k] = (u16*)alloc(CR * 256 * 2);
    CSA[k] = (u16*)alloc(CR * 256 * 2);
  }
  float* UPROJ[3];
  for (int k = 0; k < 3; ++k) UPROJ[k] = (float*)alloc(CR * 256 * 4);
  u16*   PPA   = (u16*)alloc((size_t)384 * 256 * 2);    // depths 1-2 only
  const size_t SB = (size_t)16384 * 256 * 2;
  u16* HP[2] = {(u16*)alloc(SB), (u16*)alloc(SB)};
  u16* CP[2] = {(u16*)alloc(SB), (u16*)alloc(SB)};
  u16*   GATES  = (u16*)alloc(CR * 1024 * 2);
  u16*   GATESP = (u16*)alloc((size_t)4096 * 1024 * 2);
  u16*   HPRED  = (u16*)alloc((size_t)87424 * 256 * 2); // node-ordered, +pad

  // L1: pack
  k_pack<<<8037, 256, 0, stream>>>(Upar, Whhp, Usib, Whhs, z, Wihp, Wihs,
                                   Wlab, Wd, Ww, blab, bd, bw, bihp, bhhp,
                                   bihs, bhhs, UPWHHP, USWHHS, ZBF, WIHPT,
                                   WIHST, WEXT, BE, BP, BS);
  // L2: s0 || zdual
  k_s0_zdual<<<21834, 256, 0, stream>>>(WIHST, BS, feat, HSA[0], CSA[0],
                                        ZBF, UPWHHP, HPRED, GATESP);
  // L3: sibdual1 || plstm0 (d0: 64 nodes)
  k_sibdual_plstm<<<1710 + 64, 256, 0, stream>>>(
      1710, 171, HSA[0], USWHHS, UPROJ[0], GATES,
      GATESP, WIHPT, BP, nullptr, feat, HP[0], CP[0], 0, 0);
  // L4: siblstm1 || pdual1 (PP d1, 64 rows + gatesP)
  k_siblstm_pdual<<<21824 + 10, 256, 0, stream>>>(
      1, GATES, WIHST, BS, CSA[0], feat, HSA[1], CSA[1],
      1, HP[0], UPWHHP, 64, PPA, 0, GATESP);
  // L5: sibdual2 || plstm1 (d1: 256 nodes)
  k_sibdual_plstm<<<1710 + 256, 256, 0, stream>>>(
      1710, 171, HSA[1], USWHHS, UPROJ[1], GATES,
      GATESP, WIHPT, BP, CP[0], feat, HP[1], CP[1], 2, 1);
  // L6: siblstm2 || pdual2 (PP d2, 256 rows + gatesP)
  k_siblstm_pdual<<<21824 + 20, 256, 0, stream>>>(
      2, GATES, WIHST, BS, CSA[1], feat, HSA[2], CSA[2],
      2, HP[1], UPWHHP, 256, PPA, 64, GATESP);
  // L7: sibdual3 (UPROJ only, ny=2) || plstm2 (d2: 1024 nodes)
  k_sibdual_plstm<<<342 + 1024, 256, 0, stream>>>(
      342, 171, HSA[2], USWHHS, UPROJ[2], nullptr,
      GATESP, WIHPT, BP, CP[1], feat, HP[0], CP[0], 4, 5);
  // L8: pdual3 (PP d3, 1024 rows; fused HPRED epi + gatesP)
  k_pdual_epi<<<80, 256, 0, stream>>>(8, HP[0], UPWHHP, 1024, GATESP,
                                      HPRED, UPROJ[0], UPROJ[1], UPROJ[2],
                                      320, 4, 21);
  // L9: plstm3 (d3: 4096 nodes) || assemble (rows 0..319)
  k_plstm_asm<<<4096 + 320, 256, 0, stream>>>(
      GATESP, WIHPT, BP, CP[0], feat, HP[1], CP[1],
      PPA, UPROJ[0], UPROJ[1], UPROJ[2], HPRED);
  // L10: pdual4 (PP d4, 4096 rows; fused HPRED epi + gatesP)
  k_pdual_epi<<<320, 256, 0, stream>>>(32, HP[1], UPWHHP, 4096, GATESP,
                                       HPRED, UPROJ[0], UPROJ[1], UPROJ[2],
                                       1344, 6, 85);
  // L11: plstm4 (d4: 16384 nodes)
  k_plstm<<<16384, 256, 0, stream>>>(GATESP, WIHPT, BP, CP[1], feat,
                                     HP[0], CP[0], 8, 85);
  // L12: pdual5 (PP d5, 16384 rows; fused HPRED epi, no gates, ny=2)
  k_pdual_epi<<<256, 256, 0, stream>>>(128, HP[0], UPWHHP, 16384, nullptr,
                                       HPRED, UPROJ[0], UPROJ[1], UPROJ[2],
                                       5440, 8, 341);
  // L13: fused tail
  k_mm_tail<<<2730, 256, 0, stream>>>(HPRED, WEXT, BE, out);

  (void)in_sizes; (void)n_in; (void)out_size; (void)ws_size;
}

// Round 7
// 758.226 us; speedup vs baseline: 1.1385x; 1.1385x over previous
//
#include <hip/hip_runtime.h>

// TreeLstmDecoder: B=64 trees, K=4, D=6, V=600, L=256, N_PER=1365, N=87360.
// 13-launch schedule (sibling chain and parent chain are independent; each
// launch merges one step of each via block-index branching):
//  L1  k_pack
//  L2  s0 (21824) || zdual (root hpred + gatesP)
//  L3  sibdual1 || plstm0
//  L4  siblstm1 || pdual1 (PPA d1 + gatesP)
//  L5  sibdual2 || plstm1
//  L6  siblstm2 || pdual2 (PPA d2 + gatesP)
//  L7  sibdual3 (UPROJ only) || plstm2
//  L8  pdual3  (fused HPRED epilogue + gatesP)
//  L9  plstm3 || assemble (rows 0..319, depths 1-2)
//  L10 pdual4  (fused HPRED epilogue + gatesP)
//  L11 plstm4
//  L12 pdual5  (fused HPRED epilogue, no gates)
//  L13 k_mm_tail (87360x602x256 GEMM + log-softmax, register-resident)
// All GEMMs: C = A*B^T, bf16 operands, fp32 MFMA accumulate.
// NOTE: plain (cached) stores everywhere — R6 showed nontemporal stores
// defeat L2 write-combining on 4B scattered stores (WRITE 210->389 MB).

typedef unsigned short u16;
typedef short bf16x8 __attribute__((ext_vector_type(8)));
typedef float f32x4 __attribute__((ext_vector_type(4)));

#define NPER 1365
#define VDIM 600
#define VD2  602

#define MODE_PPA   0
#define MODE_UPROJ 1
#define MODE_ROOT  2
#define MODE_EPI   3

__device__ __forceinline__ float b2f(u16 h) {
  union { unsigned u; float f; } v; v.u = ((unsigned)h) << 16; return v.f;
}
__device__ __forceinline__ u16 f2bf(float f) {
  union { float f; unsigned u; } v; v.f = f;
  unsigned r = v.u + 0x7fff + ((v.u >> 16) & 1);
  return (u16)(r >> 16);
}
__device__ __forceinline__ float fsigm(float x) {
  return __fdividef(1.f, 1.f + __expf(-x));
}
__device__ __forceinline__ float ftanh(float x) {
  float e = __expf(-2.f * fabsf(x));
  float r = __fdividef(1.f - e, 1.f + e);
  return x < 0.f ? -r : r;
}

// chain-row ladder: r -> (off, pcs, start) for depths 1..5
__device__ __forceinline__ void ladder(int r, int& off, int& pcs, int& start) {
  if (r < 64)        { off = 0;    pcs = 0; start = 1;   }
  else if (r < 320)  { off = 64;   pcs = 2; start = 5;   }
  else if (r < 1344) { off = 320;  pcs = 4; start = 21;  }
  else if (r < 5440) { off = 1344; pcs = 6; start = 85;  }
  else               { off = 5440; pcs = 8; start = 341; }
}

// ---------------- pack kernel -----------------------------------------------
__global__ void k_pack(
    const float* __restrict__ Upar, const float* __restrict__ Whhp,
    const float* __restrict__ Usib, const float* __restrict__ Whhs,
    const float* __restrict__ z, const float* __restrict__ Wihp,
    const float* __restrict__ Wihs, const float* __restrict__ Wlab,
    const float* __restrict__ Wd, const float* __restrict__ Ww,
    const float* __restrict__ blab, const float* __restrict__ bd,
    const float* __restrict__ bw, const float* __restrict__ bihp,
    const float* __restrict__ bhhp, const float* __restrict__ bihs,
    const float* __restrict__ bhhs,
    u16* __restrict__ UPWHHP, u16* __restrict__ USWHHS, u16* __restrict__ ZBF,
    u16* __restrict__ WIHPT, u16* __restrict__ WIHST, u16* __restrict__ WEXT,
    float* __restrict__ BE, float* __restrict__ BP, float* __restrict__ BS) {
  int i = blockIdx.x * 256 + threadIdx.x;
  if (i < 327680) {
    int r = i >> 8, c = i & 255;
    UPWHHP[i] = f2bf(r < 256 ? Upar[(r << 8) | c] : Whhp[((r - 256) << 8) | c]);
    return;
  }
  i -= 327680;
  if (i < 327680) {
    int r = i >> 8, c = i & 255;
    USWHHS[i] = f2bf(r < 256 ? Usib[(r << 8) | c] : Whhs[((r - 256) << 8) | c]);
    return;
  }
  i -= 327680;
  if (i < 16384) { ZBF[i] = f2bf(z[i]); return; }
  i -= 16384;
  if (i < 614400) {  // W_ih_p [1024,600] -> [600,1024]; coalesced writes
    int r = i >> 10, c = i & 1023;
    WIHPT[i] = f2bf(Wihp[c * VDIM + r]); return;
  }
  i -= 614400;
  if (i < 614400) {
    int r = i >> 10, c = i & 1023;
    WIHST[i] = f2bf(Wihs[c * VDIM + r]); return;
  }
  i -= 614400;
  if (i < VD2 * 256) {
    int r = i >> 8, c = i & 255;
    float v = (r < VDIM) ? Wlab[r * 256 + c] : ((r == VDIM) ? Wd[c] : Ww[c]);
    WEXT[i] = f2bf(v); return;
  }
  i -= VD2 * 256;
  if (i < VD2) { BE[i] = (i < VDIM) ? blab[i] : ((i == VDIM) ? bd[0] : bw[0]); return; }
  i -= VD2;
  if (i < 1024) { BP[i] = bihp[i] + bhhp[i]; return; }
  i -= 1024;
  if (i < 1024) { BS[i] = bihs[i] + bhhs[i]; return; }
}

// ---------------- dual GEMM device fn: C = A*B^T, B=[1280,256] concat -------
// n0>=256 tiles -> gates. n0<256 tiles by mode:
//  MODE_PPA  : ppa[(ppoff+row)*256+col] = bf16(acc)
//  MODE_UPROJ: uproj[row*256+col] = acc (fp32)
//  MODE_ROOT : hpred[row*NPER*256+col] = bf16(tanh(acc))
//  MODE_EPI  : node base = (row>>lsb)*NPER + startd + 4*(row&(2^lsb-1));
//              hpred rows s=0..3 = tanh(acc [+ U_s[(ppoff+row)*256+col]])
__device__ __forceinline__ void dev_dual(
    int tile, int nx, const u16* __restrict__ A, const u16* __restrict__ B,
    int M, int mode, u16* __restrict__ ppa, int ppoff,
    float* __restrict__ uproj, u16* __restrict__ gates,
    u16* __restrict__ hpred, const float* __restrict__ U1,
    const float* __restrict__ U2, const float* __restrict__ U3,
    int lsb, int startd) {
  static __shared__ __align__(16) u16 As[128 * 40];
  static __shared__ __align__(16) u16 Bs[128 * 40];
  const int m0 = (tile % nx) * 128, n0 = (tile / nx) * 128;
  const int tid = threadIdx.x;
  const int wave = tid >> 6, lane = tid & 63;
  const int quad = lane >> 4, lr = lane & 15;
  const int wm = (wave >> 1) * 64, wn = (wave & 1) * 64;
  const int srow = tid >> 2;
  const int sch = (tid & 3) << 3;

  f32x4 acc[4][4] = {};
  for (int t = 0; t < 8; ++t) {
    const int kk = t * 32;
    bf16x8 a0 = *(const bf16x8*)(A + (size_t)(m0 + srow) * 256 + kk + sch);
    bf16x8 a1 = *(const bf16x8*)(A + (size_t)(m0 + srow + 64) * 256 + kk + sch);
    bf16x8 b0 = *(const bf16x8*)(B + (size_t)(n0 + srow) * 256 + kk + sch);
    bf16x8 b1 = *(const bf16x8*)(B + (size_t)(n0 + srow + 64) * 256 + kk + sch);
    __syncthreads();
    *(bf16x8*)&As[srow * 40 + sch] = a0;
    *(bf16x8*)&As[(srow + 64) * 40 + sch] = a1;
    *(bf16x8*)&Bs[srow * 40 + sch] = b0;
    *(bf16x8*)&Bs[(srow + 64) * 40 + sch] = b1;
    __syncthreads();
    bf16x8 af[4], bfr[4];
#pragma unroll
    for (int tm = 0; tm < 4; ++tm)
      af[tm] = *(const bf16x8*)&As[(wm + tm * 16 + lr) * 40 + quad * 8];
#pragma unroll
    for (int tn = 0; tn < 4; ++tn)
      bfr[tn] = *(const bf16x8*)&Bs[(wn + tn * 16 + lr) * 40 + quad * 8];
#pragma unroll
    for (int tm = 0; tm < 4; ++tm)
#pragma unroll
      for (int tn = 0; tn < 4; ++tn)
        acc[tm][tn] = __builtin_amdgcn_mfma_f32_16x16x32_bf16(
            af[tm], bfr[tn], acc[tm][tn], 0, 0, 0);
  }

  const bool isg = (n0 >= 256);
#pragma unroll
  for (int tn = 0; tn < 4; ++tn) {
    int col = n0 + wn + tn * 16 + lr;
#pragma unroll
    for (int tm = 0; tm < 4; ++tm) {
#pragma unroll
      for (int r = 0; r < 4; ++r) {
        int row = m0 + wm + tm * 16 + quad * 4 + r;
        if (row >= M) continue;
        float v = acc[tm][tn][r];
        if (isg) {
          gates[(size_t)row * 1024 + (col - 256)] = f2bf(v);
        } else if (mode == MODE_PPA) {
          ppa[(size_t)(ppoff + row) * 256 + col] = f2bf(v);
        } else if (mode == MODE_UPROJ) {
          uproj[(size_t)row * 256 + col] = v;
        } else if (mode == MODE_ROOT) {
          hpred[(size_t)row * NPER * 256 + col] = f2bf(ftanh(v));
        } else {  // MODE_EPI
          int t2 = row >> lsb, j = row & ((1 << lsb) - 1);
          size_t bb = ((size_t)(t2 * NPER + startd + 4 * j)) * 256 + col;
          size_t ro = (size_t)(ppoff + row) * 256 + col;
          hpred[bb]       = f2bf(ftanh(v));
          hpred[bb + 256] = f2bf(ftanh(v + U1[ro]));
          hpred[bb + 512] = f2bf(ftanh(v + U2[ro]));
          hpred[bb + 768] = f2bf(ftanh(v + U3[ro]));
        }
      }
    }
  }
}

// ---------------- LSTM elementwise device fns -------------------------------

__device__ __forceinline__ void dev_s0(int r, const u16* __restrict__ wihT,
    const float* __restrict__ bias, const int* __restrict__ feat,
    u16* __restrict__ h, u16* __restrict__ c) {
  int u = threadIdx.x;
  int off, pcs, start; ladder(r, off, pcs, start);
  int lg = r - off;
  int t = lg >> pcs, j = lg & ((1 << pcs) - 1);
  int lab = feat[t * NPER + start + 4 * j];
  const u16* wr = wihT + lab * 1024;
  float gi = b2f(wr[u])       + bias[u];
  float gg = b2f(wr[512 + u]) + bias[512 + u];
  float go = b2f(wr[768 + u]) + bias[768 + u];
  float cn = fsigm(gi) * ftanh(gg);
  float hn = fsigm(go) * ftanh(cn);
  h[(size_t)r * 256 + u] = f2bf(hn);
  c[(size_t)r * 256 + u] = f2bf(cn);
}

__device__ __forceinline__ void dev_lstm_sib(int r, int k,
    const u16* __restrict__ gates, const u16* __restrict__ wihT,
    const float* __restrict__ bias, const u16* __restrict__ c_in,
    const int* __restrict__ feat, u16* __restrict__ h, u16* __restrict__ c) {
  int u = threadIdx.x;
  int off, pcs, start; ladder(r, off, pcs, start);
  int lg = r - off;
  int t = lg >> pcs, j = lg & ((1 << pcs) - 1);
  int lab = feat[t * NPER + start + 4 * j + k];
  const u16* wr = wihT + lab * 1024;
  const u16* gr = gates + (size_t)r * 1024;
  float gi = b2f(wr[u])       + bias[u]       + b2f(gr[u]);
  float gf = b2f(wr[256 + u]) + bias[256 + u] + b2f(gr[256 + u]);
  float gg = b2f(wr[512 + u]) + bias[512 + u] + b2f(gr[512 + u]);
  float go = b2f(wr[768 + u]) + bias[768 + u] + b2f(gr[768 + u]);
  float cv = b2f(c_in[(size_t)r * 256 + u]);
  float cn = fsigm(gf) * cv + fsigm(gi) * ftanh(gg);
  float hn = fsigm(go) * ftanh(cn);
  h[(size_t)r * 256 + u] = f2bf(hn);
  c[(size_t)r * 256 + u] = f2bf(cn);
}

__device__ __forceinline__ void dev_lstm_par(int g,
    const u16* __restrict__ gates, const u16* __restrict__ wihT,
    const float* __restrict__ bias, const u16* __restrict__ c_in,
    const int* __restrict__ feat, u16* __restrict__ h, u16* __restrict__ c,
    int lsbits, int start) {
  int u = threadIdx.x;
  int t = g >> lsbits, p = g & ((1 << lsbits) - 1);
  int pr = lsbits ? ((t << (lsbits - 2)) | (p >> 2)) : g;
  int lab = feat[t * NPER + start + p];
  const u16* wr = wihT + lab * 1024;
  const u16* gr = gates + (size_t)pr * 1024;
  float gi = b2f(wr[u])       + bias[u]       + b2f(gr[u]);
  float gf = b2f(wr[256 + u]) + bias[256 + u] + b2f(gr[256 + u]);
  float gg = b2f(wr[512 + u]) + bias[512 + u] + b2f(gr[512 + u]);
  float go = b2f(wr[768 + u]) + bias[768 + u] + b2f(gr[768 + u]);
  float cv = c_in ? b2f(c_in[(size_t)pr * 256 + u]) : 0.f;
  float cn = fsigm(gf) * cv + fsigm(gi) * ftanh(gg);
  float hn = fsigm(go) * ftanh(cn);
  h[(size_t)g * 256 + u] = f2bf(hn);
  c[(size_t)g * 256 + u] = f2bf(cn);
}

__device__ __forceinline__ void dev_assemble(int r,
    const u16* __restrict__ PPA, const float* __restrict__ U1,
    const float* __restrict__ U2, const float* __restrict__ U3,
    u16* __restrict__ HPRED) {
  int u = threadIdx.x;
  int off, pcs, start; ladder(r, off, pcs, start);
  int lg = r - off;
  int t = lg >> pcs, j = lg & ((1 << pcs) - 1);
  size_t base = ((size_t)(t * NPER + start + 4 * j)) * 256 + u;
  size_t ro = (size_t)r * 256 + u;
  float pp = b2f(PPA[ro]);
  HPRED[base]       = f2bf(ftanh(pp));
  HPRED[base + 256] = f2bf(ftanh(pp + U1[ro]));
  HPRED[base + 512] = f2bf(ftanh(pp + U2[ro]));
  HPRED[base + 768] = f2bf(ftanh(pp + U3[ro]));
}

// ---------------- merged launch kernels -------------------------------------

// L2: s0 (21824 blocks) || zdual (10 tiles, root hpred + gatesP)
__global__ __launch_bounds__(256) void k_s0_zdual(
    const u16* WIHST, const float* BS, const int* feat, u16* h, u16* c,
    const u16* ZBF, const u16* UPWHHP, u16* HPRED, u16* GATESP) {
  int b = blockIdx.x;
  if (b < 21824)
    dev_s0(b, WIHST, BS, feat, h, c);
  else
    dev_dual(b - 21824, 1, ZBF, UPWHHP, 64, MODE_ROOT, nullptr, 0, nullptr,
             GATESP, HPRED, nullptr, nullptr, nullptr, 0, 0);
}

// L3/L5/L7: sibdual (nSib tiles, UPROJ+gates) || plstm (nPar blocks)
__global__ __launch_bounds__(256) void k_sibdual_plstm(
    int nSib, int nx, const u16* HSAin, const u16* USWHHS,
    float* UPROJk, u16* GATES,
    const u16* GATESP, const u16* WIHPT, const float* BP, const u16* CPin,
    const int* feat, u16* HPout, u16* CPout, int lsbits, int startp) {
  int b = blockIdx.x;
  if (b < nSib)
    dev_dual(b, nx, HSAin, USWHHS, 21824, MODE_UPROJ, nullptr, 0, UPROJk,
             GATES, nullptr, nullptr, nullptr, nullptr, 0, 0);
  else
    dev_lstm_par(b - nSib, GATESP, WIHPT, BP, CPin, feat, HPout, CPout,
                 lsbits, startp);
}

// L4/L6: siblstm (21824 blocks) || pdual (PPA + gatesP)
__global__ __launch_bounds__(256) void k_siblstm_pdual(
    int kSib, const u16* GATES, const u16* WIHST, const float* BS,
    const u16* CSAin, const int* feat, u16* HSAout, u16* CSAout,
    int nx, const u16* HPin, const u16* UPWHHP, int Mpar,
    u16* PPA, int ppoff, u16* GATESP) {
  int b = blockIdx.x;
  if (b < 21824)
    dev_lstm_sib(b, kSib, GATES, WIHST, BS, CSAin, feat, HSAout, CSAout);
  else
    dev_dual(b - 21824, nx, HPin, UPWHHP, Mpar, MODE_PPA, PPA, ppoff, nullptr,
             GATESP, nullptr, nullptr, nullptr, nullptr, 0, 0);
}

// L8/L10/L12: pdual with fused HPRED epilogue (+ gatesP when ny=10)
__global__ __launch_bounds__(256) void k_pdual_epi(
    int nx, const u16* HPin, const u16* UPWHHP, int M, u16* GATESP,
    u16* HPRED, const float* U1, const float* U2, const float* U3,
    int ppoff, int lsb, int startd) {
  dev_dual(blockIdx.x, nx, HPin, UPWHHP, M, MODE_EPI, nullptr, ppoff, nullptr,
           GATESP, HPRED, U1, U2, U3, lsb, startd);
}

// L9: plstm3 (4096 blocks) || assemble (320 rows: depths 1-2)
__global__ __launch_bounds__(256) void k_plstm_asm(
    const u16* GATESP, const u16* WIHPT, const float* BP, const u16* CPin,
    const int* feat, u16* HPout, u16* CPout,
    const u16* PPA, const float* U1, const float* U2, const float* U3,
    u16* HPRED) {
  int b = blockIdx.x;
  if (b < 4096)
    dev_lstm_par(b, GATESP, WIHPT, BP, CPin, feat, HPout, CPout, 6, 21);
  else
    dev_assemble(b - 4096, PPA, U1, U2, U3, HPRED);
}

// L11: plstm4 standalone
__global__ __launch_bounds__(256) void k_plstm(
    const u16* GATESP, const u16* WIHPT, const float* BP, const u16* CPin,
    const int* feat, u16* HPout, u16* CPout, int lsbits, int start) {
  dev_lstm_par(blockIdx.x, GATESP, WIHPT, BP, CPin, feat, HPout, CPout,
               lsbits, start);
}

// ---------------- fused tail: logits GEMM + log-softmax ---------------------
__global__ __launch_bounds__(256, 2) void k_mm_tail(
    const u16* __restrict__ A, const u16* __restrict__ B,
    const float* __restrict__ bias, float* __restrict__ out) {
  __shared__ __align__(16) u16 As[32 * 264];
  __shared__ float smax[32][4], ssum[32][4], slz[32];
  const int m0 = blockIdx.x * 32;
  const int tid = threadIdx.x;
  const int wave = tid >> 6, lane = tid & 63;
  const int quad = lane >> 4, lr = lane & 15;
  const int c0 = wave * 160;

#pragma unroll
  for (int c = 0; c < 4; ++c) {
    int idx = c * 256 + tid;
    int row = idx >> 5, ch = (idx & 31) << 3;
    *(bf16x8*)&As[row * 264 + ch] =
        *(const bf16x8*)(A + (size_t)(m0 + row) * 256 + ch);
  }
  __syncthreads();

  f32x4 acc[2][10] = {};
#pragma unroll
  for (int t = 0; t < 8; ++t) {
    bf16x8 af[2], bfr[10];
#pragma unroll
    for (int tm = 0; tm < 2; ++tm)
      af[tm] = *(const bf16x8*)&As[(tm * 16 + lr) * 264 + t * 32 + quad * 8];
#pragma unroll
    for (int tn = 0; tn < 10; ++tn)
      bfr[tn] = *(const bf16x8*)(B + (size_t)(c0 + tn * 16 + lr) * 256 +
                                 t * 32 + quad * 8);
#pragma unroll
    for (int tm = 0; tm < 2; ++tm)
#pragma unroll
      for (int tn = 0; tn < 10; ++tn)
        acc[tm][tn] = __builtin_amdgcn_mfma_f32_16x16x32_bf16(
            af[tm], bfr[tn], acc[tm][tn], 0, 0, 0);
  }

  float bv[10]; bool val[10];
#pragma unroll
  for (int tn = 0; tn < 10; ++tn) {
    int col = c0 + tn * 16 + lr;
    val[tn] = (col < VDIM);
    bv[tn] = (col < VD2) ? bias[col] : 0.f;
  }

#pragma unroll
  for (int tm = 0; tm < 2; ++tm) {
#pragma unroll
    for (int r = 0; r < 4; ++r) {
      float mx = -1e30f;
#pragma unroll
      for (int tn = 0; tn < 10; ++tn)
        if (val[tn]) mx = fmaxf(mx, acc[tm][tn][r] + bv[tn]);
#pragma unroll
      for (int o = 1; o < 16; o <<= 1) mx = fmaxf(mx, __shfl_xor(mx, o, 64));
      if (lr == 0) smax[tm * 16 + quad * 4 + r][wave] = mx;
    }
  }
  __syncthreads();
#pragma unroll
  for (int tm = 0; tm < 2; ++tm) {
#pragma unroll
    for (int r = 0; r < 4; ++r) {
      int row = tm * 16 + quad * 4 + r;
      float fm = fmaxf(fmaxf(smax[row][0], smax[row][1]),
                       fmaxf(smax[row][2], smax[row][3]));
      float se = 0.f;
#pragma unroll
      for (int tn = 0; tn < 10; ++tn)
        if (val[tn]) se += __expf(acc[tm][tn][r] + bv[tn] - fm);
#pragma unroll
      for (int o = 1; o < 16; o <<= 1) se += __shfl_xor(se, o, 64);
      if (lr == 0) ssum[row][wave] = se;
    }
  }
  __syncthreads();
  if (tid < 32) {
    float fm = fmaxf(fmaxf(smax[tid][0], smax[tid][1]),
                     fmaxf(smax[tid][2], smax[tid][3]));
    slz[tid] = fm + __logf(ssum[tid][0] + ssum[tid][1] +
                           ssum[tid][2] + ssum[tid][3]);
  }
  __syncthreads();

#pragma unroll
  for (int tm = 0; tm < 2; ++tm) {
#pragma unroll
    for (int tn = 0; tn < 10; ++tn) {
      int col = c0 + tn * 16 + lr;
      if (col >= VD2) continue;
#pragma unroll
      for (int r = 0; r < 4; ++r) {
        int row = tm * 16 + quad * 4 + r;
        float v = acc[tm][tn][r] + bv[tn];
        out[(size_t)(m0 + row) * VD2 + col] =
            (col < VDIM) ? (v - slz[row]) : fsigm(v);
      }
    }
  }
}

// ---------------- host ------------------------------------------------------

extern "C" void kernel_launch(void* const* d_in, const int* in_sizes, int n_in,
                              void* d_out, int out_size, void* d_ws, size_t ws_size,
                              hipStream_t stream) {
  const float* z    = (const float*)d_in[0];
  const int*   feat = (const int*)d_in[1];
  const float* Wihp = (const float*)d_in[2];
  const float* Whhp = (const float*)d_in[3];
  const float* bihp = (const float*)d_in[4];
  const float* bhhp = (const float*)d_in[5];
  const float* Wihs = (const float*)d_in[6];
  const float* Whhs = (const float*)d_in[7];
  const float* bihs = (const float*)d_in[8];
  const float* bhhs = (const float*)d_in[9];
  const float* Upar = (const float*)d_in[10];
  const float* Usib = (const float*)d_in[11];
  const float* Wlab = (const float*)d_in[12];
  const float* blab = (const float*)d_in[13];
  const float* Wd   = (const float*)d_in[14];
  const float* bd   = (const float*)d_in[15];
  const float* Ww   = (const float*)d_in[16];
  const float* bw   = (const float*)d_in[17];
  float* out = (float*)d_out;

  char* w = (char*)d_ws;
  auto alloc = [&](size_t bytes) {
    char* p = w; w += (bytes + 255) & ~(size_t)255; return p;
  };
  u16*   UPWHHP = (u16*)alloc((size_t)1280 * 256 * 2);
  u16*   USWHHS = (u16*)alloc((size_t)1280 * 256 * 2);
  u16*   ZBF    = (u16*)alloc((size_t)128 * 256 * 2);   // rows 64..127 pad
  u16*   WIHPT  = (u16*)alloc((size_t)VDIM * 1024 * 2);
  u16*   WIHST  = (u16*)alloc((size_t)VDIM * 1024 * 2);
  u16*   WEXT   = (u16*)alloc((size_t)640 * 256 * 2);   // rows 602..639 pad
  float* BE     = (float*)alloc(VD2 * 4);
  float* BP     = (float*)alloc(1024 * 4);
  float* BS     = (float*)alloc(1024 * 4);
  const size_t CR = 21888;                              // 171*128 chain rows
  u16*   HSA[3], *CSA[3];
  for (int k = 0; k < 3; ++k) {
    HSA[k] = (u16*)alloc(CR * 256 * 2);
    CSA[k] = (u16*)alloc(CR * 256 * 2);
  }
  float* UPROJ[3];
  for (int k = 0; k < 3; ++k) UPROJ[k] = (float*)alloc(CR * 256 * 4);
  u16*   PPA   = (u16*)alloc((size_t)384 * 256 * 2);    // depths 1-2 only
  const size_t SB = (size_t)16384 * 256 * 2;
  u16* HP[2] = {(u16*)alloc(SB), (u16*)alloc(SB)};
  u16* CP[2] = {(u16*)alloc(SB), (u16*)alloc(SB)};
  u16*   GATES  = (u16*)alloc(CR * 1024 * 2);
  u16*   GATESP = (u16*)alloc((size_t)4096 * 1024 * 2);
  u16*   HPRED  = (u16*)alloc((size_t)87424 * 256 * 2); // node-ordered, +pad

  // L1: pack
  k_pack<<<8037, 256, 0, stream>>>(Upar, Whhp, Usib, Whhs, z, Wihp, Wihs,
                                   Wlab, Wd, Ww, blab, bd, bw, bihp, bhhp,
                                   bihs, bhhs, UPWHHP, USWHHS, ZBF, WIHPT,
                                   WIHST, WEXT, BE, BP, BS);
  // L2: s0 || zdual
  k_s0_zdual<<<21834, 256, 0, stream>>>(WIHST, BS, feat, HSA[0], CSA[0],
                                        ZBF, UPWHHP, HPRED, GATESP);
  // L3: sibdual1 || plstm0 (d0: 64 nodes)
  k_sibdual_plstm<<<1710 + 64, 256, 0, stream>>>(
      1710, 171, HSA[0], USWHHS, UPROJ[0], GATES,
      GATESP, WIHPT, BP, nullptr, feat, HP[0], CP[0], 0, 0);
  // L4: siblstm1 || pdual1 (PP d1, 64 rows + gatesP)
  k_siblstm_pdual<<<21824 + 10, 256, 0, stream>>>(
      1, GATES, WIHST, BS, CSA[0], feat, HSA[1], CSA[1],
      1, HP[0], UPWHHP, 64, PPA, 0, GATESP);
  // L5: sibdual2 || plstm1 (d1: 256 nodes)
  k_sibdual_plstm<<<1710 + 256, 256, 0, stream>>>(
      1710, 171, HSA[1], USWHHS, UPROJ[1], GATES,
      GATESP, WIHPT, BP, CP[0], feat, HP[1], CP[1], 2, 1);
  // L6: siblstm2 || pdual2 (PP d2, 256 rows + gatesP)
  k_siblstm_pdual<<<21824 + 20, 256, 0, stream>>>(
      2, GATES, WIHST, BS, CSA[1], feat, HSA[2], CSA[2],
      2, HP[1], UPWHHP, 256, PPA, 64, GATESP);
  // L7: sibdual3 (UPROJ only, ny=2) || plstm2 (d2: 1024 nodes)
  k_sibdual_plstm<<<342 + 1024, 256, 0, stream>>>(
      342, 171, HSA[2], USWHHS, UPROJ[2], nullptr,
      GATESP, WIHPT, BP, CP[1], feat, HP[0], CP[0], 4, 5);
  // L8: pdual3 (PP d3, 1024 rows; fused HPRED epi + gatesP)
  k_pdual_epi<<<80, 256, 0, stream>>>(8, HP[0], UPWHHP, 1024, GATESP,
                                      HPRED, UPROJ[0], UPROJ[1], UPROJ[2],
                                      320, 4, 21);
  // L9: plstm3 (d3: 4096 nodes) || assemble (rows 0..319)
  k_plstm_asm<<<4096 + 320, 256, 0, stream>>>(
      GATESP, WIHPT, BP, CP[0], feat, HP[1], CP[1],
      PPA, UPROJ[0], UPROJ[1], UPROJ[2], HPRED);
  // L10: pdual4 (PP d4, 4096 rows; fused HPRED epi + gatesP)
  k_pdual_epi<<<320, 256, 0, stream>>>(32, HP[1], UPWHHP, 4096, GATESP,
                                       HPRED, UPROJ[0], UPROJ[1], UPROJ[2],
                                       1344, 6, 85);
  // L11: plstm4 (d4: 16384 nodes)
  k_plstm<<<16384, 256, 0, stream>>>(GATESP, WIHPT, BP, CP[1], feat,
                                     HP[0], CP[0], 8, 85);
  // L12: pdual5 (PP d5, 16384 rows; fused HPRED epi, no gates, ny=2)
  k_pdual_epi<<<256, 256, 0, stream>>>(128, HP[0], UPWHHP, 16384, nullptr,
                                       HPRED, UPROJ[0], UPROJ[1], UPROJ[2],
                                       5440, 8, 341);
  // L13: fused tail
  k_mm_tail<<<2730, 256, 0, stream>>>(HPRED, WEXT, BE, out);

  (void)in_sizes; (void)n_in; (void)out_size; (void)ws_size;
}

// Round 8
// 727.197 us; speedup vs baseline: 1.1871x; 1.0427x over previous
//
#include <hip/hip_runtime.h>

// TreeLstmDecoder: B=64 trees, K=4, D=6, V=600, L=256, N_PER=1365, N=87360.
// 14-launch schedule. Merges pair ONLY like with like (GEMM||GEMM share the
// 20KB LDS; LSTM||LSTM have none) — R7 showed mixing poisons the elementwise
// kernels' occupancy via the GEMM path's static LDS.
//  L1  k_pack
//  L2  k_s0            (21824 sibling s=0 states, LDS-free)
//  L3  zdual || sibdual1     [GEMM: HROOT+gatesP ; UPROJ1+gates]
//  L4  plstm0 || siblstm1    [LSTM, LDS-free]
//  L5  pdual1 || sibdual2    [GEMM: PPA d1+gatesP ; UPROJ2+gates]
//  L6  plstm1 || siblstm2
//  L7  pdual2 || sibdual3    [GEMM: PPA d2+gatesP ; UPROJ3 only]
//  L8..L13  plstm2, pdual3, plstm3, pdual4, plstm4, pdual5 (serial parent)
//  L14 k_tail16: 87360x602x256 GEMM + log-softmax; A-staging computes
//      hpred = tanh(PPA[r] (+ UPROJ_s[r])) ON THE FLY (assemble fused into
//      staging, 5460-block parallel; HPRED buffer eliminated). 16 rows/block
//      (acc[1][10] = 40 AGPR) for ~2x occupancy vs the 32-row version.
// All GEMMs: C = A*B^T, bf16 operands, fp32 MFMA accumulate. Plain stores
// (R6: nontemporal breaks L2 write-combining on 4B scattered stores).

typedef unsigned short u16;
typedef short bf16x8 __attribute__((ext_vector_type(8)));
typedef float f32x4 __attribute__((ext_vector_type(4)));

#define NPER 1365
#define VDIM 600
#define VD2  602

#define MODE_PPA   0
#define MODE_UPROJ 1
#define MODE_ROOT  2

__device__ __forceinline__ float b2f(u16 h) {
  union { unsigned u; float f; } v; v.u = ((unsigned)h) << 16; return v.f;
}
__device__ __forceinline__ u16 f2bf(float f) {
  union { float f; unsigned u; } v; v.f = f;
  unsigned r = v.u + 0x7fff + ((v.u >> 16) & 1);
  return (u16)(r >> 16);
}
__device__ __forceinline__ float fsigm(float x) {
  return __fdividef(1.f, 1.f + __expf(-x));
}
__device__ __forceinline__ float ftanh(float x) {
  float e = __expf(-2.f * fabsf(x));
  float r = __fdividef(1.f - e, 1.f + e);
  return x < 0.f ? -r : r;
}

// chain-row ladder: r -> (off, pcs, start) for depths 1..5
__device__ __forceinline__ void ladder(int r, int& off, int& pcs, int& start) {
  if (r < 64)        { off = 0;    pcs = 0; start = 1;   }
  else if (r < 320)  { off = 64;   pcs = 2; start = 5;   }
  else if (r < 1344) { off = 320;  pcs = 4; start = 21;  }
  else if (r < 5440) { off = 1344; pcs = 6; start = 85;  }
  else               { off = 5440; pcs = 8; start = 341; }
}

// ---------------- pack kernel -----------------------------------------------
__global__ void k_pack(
    const float* __restrict__ Upar, const float* __restrict__ Whhp,
    const float* __restrict__ Usib, const float* __restrict__ Whhs,
    const float* __restrict__ z, const float* __restrict__ Wihp,
    const float* __restrict__ Wihs, const float* __restrict__ Wlab,
    const float* __restrict__ Wd, const float* __restrict__ Ww,
    const float* __restrict__ blab, const float* __restrict__ bd,
    const float* __restrict__ bw, const float* __restrict__ bihp,
    const float* __restrict__ bhhp, const float* __restrict__ bihs,
    const float* __restrict__ bhhs,
    u16* __restrict__ UPWHHP, u16* __restrict__ USWHHS, u16* __restrict__ ZBF,
    u16* __restrict__ WIHPT, u16* __restrict__ WIHST, u16* __restrict__ WEXT,
    float* __restrict__ BE, float* __restrict__ BP, float* __restrict__ BS) {
  int i = blockIdx.x * 256 + threadIdx.x;
  if (i < 327680) {
    int r = i >> 8, c = i & 255;
    UPWHHP[i] = f2bf(r < 256 ? Upar[(r << 8) | c] : Whhp[((r - 256) << 8) | c]);
    return;
  }
  i -= 327680;
  if (i < 327680) {
    int r = i >> 8, c = i & 255;
    USWHHS[i] = f2bf(r < 256 ? Usib[(r << 8) | c] : Whhs[((r - 256) << 8) | c]);
    return;
  }
  i -= 327680;
  if (i < 16384) { ZBF[i] = f2bf(z[i]); return; }
  i -= 16384;
  if (i < 614400) {  // W_ih_p [1024,600] -> [600,1024]; coalesced writes
    int r = i >> 10, c = i & 1023;
    WIHPT[i] = f2bf(Wihp[c * VDIM + r]); return;
  }
  i -= 614400;
  if (i < 614400) {
    int r = i >> 10, c = i & 1023;
    WIHST[i] = f2bf(Wihs[c * VDIM + r]); return;
  }
  i -= 614400;
  if (i < VD2 * 256) {
    int r = i >> 8, c = i & 255;
    float v = (r < VDIM) ? Wlab[r * 256 + c] : ((r == VDIM) ? Wd[c] : Ww[c]);
    WEXT[i] = f2bf(v); return;
  }
  i -= VD2 * 256;
  if (i < VD2) { BE[i] = (i < VDIM) ? blab[i] : ((i == VDIM) ? bd[0] : bw[0]); return; }
  i -= VD2;
  if (i < 1024) { BP[i] = bihp[i] + bhhp[i]; return; }
  i -= 1024;
  if (i < 1024) { BS[i] = bihs[i] + bhhs[i]; return; }
}

// ---------------- dual GEMM device fn: C = A*B^T, B=[1280,256] concat -------
// n0>=256 tiles -> gates (bf16 raw). n0<256 tiles by mode:
//  MODE_PPA  : ppa[(ppoff+row)*256+col] = bf16(acc)
//  MODE_UPROJ: uproj[row*256+col] = acc (fp32)
//  MODE_ROOT : hroot[row*256+col] = bf16(tanh(acc))   (compact 64x256)
__device__ __forceinline__ void dev_dual(
    int tile, int nx, const u16* __restrict__ A, const u16* __restrict__ B,
    int M, int mode, u16* __restrict__ ppa, int ppoff,
    float* __restrict__ uproj, u16* __restrict__ gates,
    u16* __restrict__ hroot) {
  static __shared__ __align__(16) u16 As[128 * 40];
  static __shared__ __align__(16) u16 Bs[128 * 40];
  const int m0 = (tile % nx) * 128, n0 = (tile / nx) * 128;
  const int tid = threadIdx.x;
  const int wave = tid >> 6, lane = tid & 63;
  const int quad = lane >> 4, lr = lane & 15;
  const int wm = (wave >> 1) * 64, wn = (wave & 1) * 64;
  const int srow = tid >> 2;
  const int sch = (tid & 3) << 3;

  f32x4 acc[4][4] = {};
  for (int t = 0; t < 8; ++t) {
    const int kk = t * 32;
    bf16x8 a0 = *(const bf16x8*)(A + (size_t)(m0 + srow) * 256 + kk + sch);
    bf16x8 a1 = *(const bf16x8*)(A + (size_t)(m0 + srow + 64) * 256 + kk + sch);
    bf16x8 b0 = *(const bf16x8*)(B + (size_t)(n0 + srow) * 256 + kk + sch);
    bf16x8 b1 = *(const bf16x8*)(B + (size_t)(n0 + srow + 64) * 256 + kk + sch);
    __syncthreads();
    *(bf16x8*)&As[srow * 40 + sch] = a0;
    *(bf16x8*)&As[(srow + 64) * 40 + sch] = a1;
    *(bf16x8*)&Bs[srow * 40 + sch] = b0;
    *(bf16x8*)&Bs[(srow + 64) * 40 + sch] = b1;
    __syncthreads();
    bf16x8 af[4], bfr[4];
#pragma unroll
    for (int tm = 0; tm < 4; ++tm)
      af[tm] = *(const bf16x8*)&As[(wm + tm * 16 + lr) * 40 + quad * 8];
#pragma unroll
    for (int tn = 0; tn < 4; ++tn)
      bfr[tn] = *(const bf16x8*)&Bs[(wn + tn * 16 + lr) * 40 + quad * 8];
#pragma unroll
    for (int tm = 0; tm < 4; ++tm)
#pragma unroll
      for (int tn = 0; tn < 4; ++tn)
        acc[tm][tn] = __builtin_amdgcn_mfma_f32_16x16x32_bf16(
            af[tm], bfr[tn], acc[tm][tn], 0, 0, 0);
  }

  const bool isg = (n0 >= 256);
#pragma unroll
  for (int tn = 0; tn < 4; ++tn) {
    int col = n0 + wn + tn * 16 + lr;
#pragma unroll
    for (int tm = 0; tm < 4; ++tm) {
#pragma unroll
      for (int r = 0; r < 4; ++r) {
        int row = m0 + wm + tm * 16 + quad * 4 + r;
        if (row >= M) continue;
        float v = acc[tm][tn][r];
        if (isg) {
          gates[(size_t)row * 1024 + (col - 256)] = f2bf(v);
        } else if (mode == MODE_PPA) {
          ppa[(size_t)(ppoff + row) * 256 + col] = f2bf(v);
        } else if (mode == MODE_UPROJ) {
          uproj[(size_t)row * 256 + col] = v;
        } else {  // MODE_ROOT
          hroot[(size_t)row * 256 + col] = f2bf(ftanh(v));
        }
      }
    }
  }
}

// ---------------- LSTM elementwise device fns (no LDS) ----------------------

__device__ __forceinline__ void dev_s0(int r, const u16* __restrict__ wihT,
    const float* __restrict__ bias, const int* __restrict__ feat,
    u16* __restrict__ h, u16* __restrict__ c) {
  int u = threadIdx.x;
  int off, pcs, start; ladder(r, off, pcs, start);
  int lg = r - off;
  int t = lg >> pcs, j = lg & ((1 << pcs) - 1);
  int lab = feat[t * NPER + start + 4 * j];
  const u16* wr = wihT + lab * 1024;
  float gi = b2f(wr[u])       + bias[u];
  float gg = b2f(wr[512 + u]) + bias[512 + u];
  float go = b2f(wr[768 + u]) + bias[768 + u];
  float cn = fsigm(gi) * ftanh(gg);
  float hn = fsigm(go) * ftanh(cn);
  h[(size_t)r * 256 + u] = f2bf(hn);
  c[(size_t)r * 256 + u] = f2bf(cn);
}

__device__ __forceinline__ void dev_lstm_sib(int r, int k,
    const u16* __restrict__ gates, const u16* __restrict__ wihT,
    const float* __restrict__ bias, const u16* __restrict__ c_in,
    const int* __restrict__ feat, u16* __restrict__ h, u16* __restrict__ c) {
  int u = threadIdx.x;
  int off, pcs, start; ladder(r, off, pcs, start);
  int lg = r - off;
  int t = lg >> pcs, j = lg & ((1 << pcs) - 1);
  int lab = feat[t * NPER + start + 4 * j + k];
  const u16* wr = wihT + lab * 1024;
  const u16* gr = gates + (size_t)r * 1024;
  float gi = b2f(wr[u])       + bias[u]       + b2f(gr[u]);
  float gf = b2f(wr[256 + u]) + bias[256 + u] + b2f(gr[256 + u]);
  float gg = b2f(wr[512 + u]) + bias[512 + u] + b2f(gr[512 + u]);
  float go = b2f(wr[768 + u]) + bias[768 + u] + b2f(gr[768 + u]);
  float cv = b2f(c_in[(size_t)r * 256 + u]);
  float cn = fsigm(gf) * cv + fsigm(gi) * ftanh(gg);
  float hn = fsigm(go) * ftanh(cn);
  h[(size_t)r * 256 + u] = f2bf(hn);
  c[(size_t)r * 256 + u] = f2bf(cn);
}

__device__ __forceinline__ void dev_lstm_par(int g,
    const u16* __restrict__ gates, const u16* __restrict__ wihT,
    const float* __restrict__ bias, const u16* __restrict__ c_in,
    const int* __restrict__ feat, u16* __restrict__ h, u16* __restrict__ c,
    int lsbits, int start) {
  int u = threadIdx.x;
  int t = g >> lsbits, p = g & ((1 << lsbits) - 1);
  int pr = lsbits ? ((t << (lsbits - 2)) | (p >> 2)) : g;
  int lab = feat[t * NPER + start + p];
  const u16* wr = wihT + lab * 1024;
  const u16* gr = gates + (size_t)pr * 1024;
  float gi = b2f(wr[u])       + bias[u]       + b2f(gr[u]);
  float gf = b2f(wr[256 + u]) + bias[256 + u] + b2f(gr[256 + u]);
  float gg = b2f(wr[512 + u]) + bias[512 + u] + b2f(gr[512 + u]);
  float go = b2f(wr[768 + u]) + bias[768 + u] + b2f(gr[768 + u]);
  float cv = c_in ? b2f(c_in[(size_t)pr * 256 + u]) : 0.f;
  float cn = fsigm(gf) * cv + fsigm(gi) * ftanh(gg);
  float hn = fsigm(go) * ftanh(cn);
  h[(size_t)g * 256 + u] = f2bf(hn);
  c[(size_t)g * 256 + u] = f2bf(cn);
}

// ---------------- launch kernels --------------------------------------------

__global__ __launch_bounds__(256) void k_s0(
    const u16* WIHST, const float* BS, const int* feat, u16* h, u16* c) {
  dev_s0(blockIdx.x, WIHST, BS, feat, h, c);
}

// GEMM || GEMM (shared 20KB LDS via dev_dual's function-local statics)
__global__ __launch_bounds__(256) void k_gg(
    int nA,
    const u16* Aa, const u16* Ba, int Ma, int nxa, int modea,
    u16* ppaa, int ppoffa, float* uproja, u16* gatesa, u16* hroota,
    const u16* Ab, const u16* Bb, int Mb, int nxb, int modeb,
    u16* ppab, int ppoffb, float* uprojb, u16* gatesb, u16* hrootb) {
  int b = blockIdx.x;
  if (b < nA)
    dev_dual(b, nxa, Aa, Ba, Ma, modea, ppaa, ppoffa, uproja, gatesa, hroota);
  else
    dev_dual(b - nA, nxb, Ab, Bb, Mb, modeb, ppab, ppoffb, uprojb, gatesb,
             hrootb);
}

// GEMM standalone
__global__ __launch_bounds__(256) void k_gemm(
    const u16* A, const u16* B, int M, int nx, int mode,
    u16* ppa, int ppoff, float* uproj, u16* gates, u16* hroot) {
  dev_dual(blockIdx.x, nx, A, B, M, mode, ppa, ppoff, uproj, gates, hroot);
}

// LSTM || LSTM (no LDS)
__global__ __launch_bounds__(256) void k_ll(
    int nP,
    const u16* gatesP, const u16* WIHPT, const float* BP, const u16* cpin,
    u16* hpout, u16* cpout, int lsbits, int startp,
    int kS, const u16* gatesS, const u16* WIHST, const float* BS,
    const u16* csin, u16* hsout, u16* csout, const int* feat) {
  int b = blockIdx.x;
  if (b < nP)
    dev_lstm_par(b, gatesP, WIHPT, BP, cpin, feat, hpout, cpout, lsbits,
                 startp);
  else
    dev_lstm_sib(b - nP, kS, gatesS, WIHST, BS, csin, feat, hsout, csout);
}

// LSTM standalone
__global__ __launch_bounds__(256) void k_plstm(
    const u16* gatesP, const u16* WIHPT, const float* BP, const u16* cpin,
    const int* feat, u16* hpout, u16* cpout, int lsbits, int start) {
  dev_lstm_par(blockIdx.x, gatesP, WIHPT, BP, cpin, feat, hpout, cpout,
               lsbits, start);
}

// ---------------- fused tail: assemble + logits GEMM + log-softmax ----------
// 16 rows/block (5460 blocks). A-staging computes hpred on the fly:
//   node = m0+row; t = node/NPER; q = node%NPER
//   q==0 -> HROOT[t]; else r = off + (t<<pcs) + (q-start)/4, s = (q-start)&3,
//   hpred = tanh(PPA[r] + (s ? UPROJ_{s}[r] : 0)).
// Wave w owns cols [w*160, w*160+160) as 10 col-tiles; acc[10] f32x4/thread.
__global__ __launch_bounds__(256, 4) void k_tail16(
    const u16* __restrict__ HROOT, const u16* __restrict__ PPA,
    const float* __restrict__ U1, const float* __restrict__ U2,
    const float* __restrict__ U3, const u16* __restrict__ B,
    const float* __restrict__ bias, float* __restrict__ out) {
  __shared__ __align__(16) u16 As[16 * 264];
  __shared__ float smax[16][4], ssum[16][4], slz[16];
  const int m0 = blockIdx.x * 16;
  const int tid = threadIdx.x;
  const int wave = tid >> 6, lane = tid & 63;
  const int quad = lane >> 4, lr = lane & 15;
  const int c0 = wave * 160;

  // staging with fused assemble (32 elems/thread in 2 chunks of bf16x8)
#pragma unroll
  for (int cch = 0; cch < 2; ++cch) {
    int idx = cch * 256 + tid;
    int row = idx >> 5, ch = (idx & 31) << 3;
    int node = m0 + row;
    int t = node / NPER;
    int q = node - t * NPER;
    bf16x8 v8;
    if (q == 0) {
      v8 = *(const bf16x8*)(HROOT + (size_t)t * 256 + ch);
    } else {
      int off, pcs, start;
      if (q < 5)        { off = 0;    pcs = 0; start = 1;   }
      else if (q < 21)  { off = 64;   pcs = 2; start = 5;   }
      else if (q < 85)  { off = 320;  pcs = 4; start = 21;  }
      else if (q < 341) { off = 1344; pcs = 6; start = 85;  }
      else              { off = 5440; pcs = 8; start = 341; }
      int qq = q - start;
      int s = qq & 3, j = qq >> 2;
      int r = off + (t << pcs) + j;
      size_t ro = (size_t)r * 256 + ch;
      bf16x8 pp = *(const bf16x8*)(PPA + ro);
      const float* Us = (s == 1) ? U1 : ((s == 2) ? U2 : U3);
#pragma unroll
      for (int e = 0; e < 8; ++e) {
        float v = b2f((u16)pp[e]);
        if (s) v += Us[ro + e];
        v8[e] = (short)f2bf(ftanh(v));
      }
    }
    *(bf16x8*)&As[row * 264 + ch] = v8;
  }
  __syncthreads();

  f32x4 acc[10] = {};
#pragma unroll
  for (int t = 0; t < 8; ++t) {
    bf16x8 af = *(const bf16x8*)&As[lr * 264 + t * 32 + quad * 8];
    bf16x8 bfr[10];
#pragma unroll
    for (int tn = 0; tn < 10; ++tn)
      bfr[tn] = *(const bf16x8*)(B + (size_t)(c0 + tn * 16 + lr) * 256 +
                                 t * 32 + quad * 8);
#pragma unroll
    for (int tn = 0; tn < 10; ++tn)
      acc[tn] = __builtin_amdgcn_mfma_f32_16x16x32_bf16(af, bfr[tn], acc[tn],
                                                        0, 0, 0);
  }

  float bv[10]; bool val[10];
#pragma unroll
  for (int tn = 0; tn < 10; ++tn) {
    int col = c0 + tn * 16 + lr;
    val[tn] = (col < VDIM);
    bv[tn] = (col < VD2) ? bias[col] : 0.f;
  }

  // per-row max: thread-local over tn, shfl within 16-lane group, LDS x-wave
#pragma unroll
  for (int r = 0; r < 4; ++r) {
    float mx = -1e30f;
#pragma unroll
    for (int tn = 0; tn < 10; ++tn)
      if (val[tn]) mx = fmaxf(mx, acc[tn][r] + bv[tn]);
#pragma unroll
    for (int o = 1; o < 16; o <<= 1) mx = fmaxf(mx, __shfl_xor(mx, o, 64));
    if (lr == 0) smax[quad * 4 + r][wave] = mx;
  }
  __syncthreads();
#pragma unroll
  for (int r = 0; r < 4; ++r) {
    int row = quad * 4 + r;
    float fm = fmaxf(fmaxf(smax[row][0], smax[row][1]),
                     fmaxf(smax[row][2], smax[row][3]));
    float se = 0.f;
#pragma unroll
    for (int tn = 0; tn < 10; ++tn)
      if (val[tn]) se += __expf(acc[tn][r] + bv[tn] - fm);
#pragma unroll
    for (int o = 1; o < 16; o <<= 1) se += __shfl_xor(se, o, 64);
    if (lr == 0) ssum[row][wave] = se;
  }
  __syncthreads();
  if (tid < 16) {
    float fm = fmaxf(fmaxf(smax[tid][0], smax[tid][1]),
                     fmaxf(smax[tid][2], smax[tid][3]));
    slz[tid] = fm + __logf(ssum[tid][0] + ssum[tid][1] +
                           ssum[tid][2] + ssum[tid][3]);
  }
  __syncthreads();

#pragma unroll
  for (int tn = 0; tn < 10; ++tn) {
    int col = c0 + tn * 16 + lr;
    if (col >= VD2) continue;
#pragma unroll
    for (int r = 0; r < 4; ++r) {
      int row = quad * 4 + r;
      float v = acc[tn][r] + bv[tn];
      out[(size_t)(m0 + row) * VD2 + col] =
          (col < VDIM) ? (v - slz[row]) : fsigm(v);
    }
  }
}

// ---------------- host ------------------------------------------------------

extern "C" void kernel_launch(void* const* d_in, const int* in_sizes, int n_in,
                              void* d_out, int out_size, void* d_ws, size_t ws_size,
                              hipStream_t stream) {
  const float* z    = (const float*)d_in[0];
  const int*   feat = (const int*)d_in[1];
  const float* Wihp = (const float*)d_in[2];
  const float* Whhp = (const float*)d_in[3];
  const float* bihp = (const float*)d_in[4];
  const float* bhhp = (const float*)d_in[5];
  const float* Wihs = (const float*)d_in[6];
  const float* Whhs = (const float*)d_in[7];
  const float* bihs = (const float*)d_in[8];
  const float* bhhs = (const float*)d_in[9];
  const float* Upar = (const float*)d_in[10];
  const float* Usib = (const float*)d_in[11];
  const float* Wlab = (const float*)d_in[12];
  const float* blab = (const float*)d_in[13];
  const float* Wd   = (const float*)d_in[14];
  const float* bd   = (const float*)d_in[15];
  const float* Ww   = (const float*)d_in[16];
  const float* bw   = (const float*)d_in[17];
  float* out = (float*)d_out;

  char* w = (char*)d_ws;
  auto alloc = [&](size_t bytes) {
    char* p = w; w += (bytes + 255) & ~(size_t)255; return p;
  };
  u16*   UPWHHP = (u16*)alloc((size_t)1280 * 256 * 2);
  u16*   USWHHS = (u16*)alloc((size_t)1280 * 256 * 2);
  u16*   ZBF    = (u16*)alloc((size_t)128 * 256 * 2);   // rows 64..127 pad
  u16*   WIHPT  = (u16*)alloc((size_t)VDIM * 1024 * 2);
  u16*   WIHST  = (u16*)alloc((size_t)VDIM * 1024 * 2);
  u16*   WEXT   = (u16*)alloc((size_t)640 * 256 * 2);   // rows 602..639 pad
  float* BE     = (float*)alloc(VD2 * 4);
  float* BP     = (float*)alloc(1024 * 4);
  float* BS     = (float*)alloc(1024 * 4);
  const size_t CR = 21888;                              // 171*128 chain rows
  u16*   HSA[3], *CSA[3];
  for (int k = 0; k < 3; ++k) {
    HSA[k] = (u16*)alloc(CR * 256 * 2);
    CSA[k] = (u16*)alloc(CR * 256 * 2);
  }
  float* UPROJ[3];
  for (int k = 0; k < 3; ++k) UPROJ[k] = (float*)alloc(CR * 256 * 4);
  u16*   PPA   = (u16*)alloc(CR * 256 * 2);             // all chain rows
  u16*   HROOT = (u16*)alloc((size_t)64 * 256 * 2);
  const size_t SB = (size_t)16384 * 256 * 2;
  u16* HP[2] = {(u16*)alloc(SB), (u16*)alloc(SB)};
  u16* CP[2] = {(u16*)alloc(SB), (u16*)alloc(SB)};
  u16*   GATES  = (u16*)alloc(CR * 1024 * 2);
  u16*   GATESP = (u16*)alloc((size_t)4096 * 1024 * 2);

  // L1: pack
  k_pack<<<8037, 256, 0, stream>>>(Upar, Whhp, Usib, Whhs, z, Wihp, Wihs,
                                   Wlab, Wd, Ww, blab, bd, bw, bihp, bhhp,
                                   bihs, bhhs, UPWHHP, USWHHS, ZBF, WIHPT,
                                   WIHST, WEXT, BE, BP, BS);
  // L2: s0 (LDS-free, full occupancy)
  k_s0<<<21824, 256, 0, stream>>>(WIHST, BS, feat, HSA[0], CSA[0]);
  // L3: zdual (10) || sibdual1 (1710)
  k_gg<<<10 + 1710, 256, 0, stream>>>(
      10,
      ZBF, UPWHHP, 64, 1, MODE_ROOT, nullptr, 0, nullptr, GATESP, HROOT,
      HSA[0], USWHHS, 21824, 171, MODE_UPROJ, nullptr, 0, UPROJ[0], GATES,
      nullptr);
  // L4: plstm0 (64) || siblstm1 (21824)
  k_ll<<<64 + 21824, 256, 0, stream>>>(
      64, GATESP, WIHPT, BP, nullptr, HP[0], CP[0], 0, 0,
      1, GATES, WIHST, BS, CSA[0], HSA[1], CSA[1], feat);
  // L5: pdual1 (10) || sibdual2 (1710)
  k_gg<<<10 + 1710, 256, 0, stream>>>(
      10,
      HP[0], UPWHHP, 64, 1, MODE_PPA, PPA, 0, nullptr, GATESP, nullptr,
      HSA[1], USWHHS, 21824, 171, MODE_UPROJ, nullptr, 0, UPROJ[1], GATES,
      nullptr);
  // L6: plstm1 (256) || siblstm2 (21824)
  k_ll<<<256 + 21824, 256, 0, stream>>>(
      256, GATESP, WIHPT, BP, CP[0], HP[1], CP[1], 2, 1,
      2, GATES, WIHST, BS, CSA[1], HSA[2], CSA[2], feat);
  // L7: pdual2 (20) || sibdual3 (342, UPROJ only)
  k_gg<<<20 + 342, 256, 0, stream>>>(
      20,
      HP[1], UPWHHP, 256, 2, MODE_PPA, PPA, 64, nullptr, GATESP, nullptr,
      HSA[2], USWHHS, 21824, 171, MODE_UPROJ, nullptr, 0, UPROJ[2], nullptr,
      nullptr);
  // L8: plstm2 (1024)
  k_plstm<<<1024, 256, 0, stream>>>(GATESP, WIHPT, BP, CP[1], feat,
                                    HP[0], CP[0], 4, 5);
  // L9: pdual3 (80)
  k_gemm<<<80, 256, 0, stream>>>(HP[0], UPWHHP, 1024, 8, MODE_PPA,
                                 PPA, 320, nullptr, GATESP, nullptr);
  // L10: plstm3 (4096)
  k_plstm<<<4096, 256, 0, stream>>>(GATESP, WIHPT, BP, CP[0], feat,
                                    HP[1], CP[1], 6, 21);
  // L11: pdual4 (320)
  k_gemm<<<320, 256, 0, stream>>>(HP[1], UPWHHP, 4096, 32, MODE_PPA,
                                  PPA, 1344, nullptr, GATESP, nullptr);
  // L12: plstm4 (16384)
  k_plstm<<<16384, 256, 0, stream>>>(GATESP, WIHPT, BP, CP[1], feat,
                                     HP[0], CP[0], 8, 85);
  // L13: pdual5 (256, PPA only, ny=2)
  k_gemm<<<256, 256, 0, stream>>>(HP[0], UPWHHP, 16384, 128, MODE_PPA,
                                  PPA, 5440, nullptr, nullptr, nullptr);
  // L14: fused tail (assemble + GEMM + log-softmax)
  k_tail16<<<5460, 256, 0, stream>>>(HROOT, PPA, UPROJ[0], UPROJ[1], UPROJ[2],
                                     WEXT, BE, out);

  (void)in_sizes; (void)n_in; (void)out_size; (void)ws_size;
}

// Round 9
// 657.397 us; speedup vs baseline: 1.3131x; 1.1062x over previous
//
#include <hip/hip_runtime.h>

// TreeLstmDecoder: B=64 trees, K=4, D=6, V=600, L=256, N_PER=1365, N=87360.
// 14-launch schedule. Mid (L1-L13) = R8's like-with-like merge schedule
// (GEMM||GEMM share the 20KB LDS; LSTM||LSTM are LDS-free) - measured 446us.
// Tail = R7's 32-row register-resident GEMM+log-softmax (measured 149us as
// HPRED-reader) with assemble fused into A-staging (HPRED eliminated).
//  L1  k_pack
//  L2  k_s0            (21824 sibling s=0 states, LDS-free)
//  L3  zdual || sibdual1     [GEMM: HROOT+gatesP ; UPROJ1+gates]
//  L4  plstm0 || siblstm1    [LSTM, LDS-free]
//  L5  pdual1 || sibdual2    [GEMM: PPA d1+gatesP ; UPROJ2+gates]
//  L6  plstm1 || siblstm2
//  L7  pdual2 || sibdual3    [GEMM: PPA d2+gatesP ; UPROJ3 only]
//  L8..L13  plstm2, pdual3, plstm3, pdual4, plstm4, pdual5 (serial parent)
//  L14 k_tail32: staging computes hpred = tanh(PPA[r] (+UPROJ_s[r])) on the
//      fly (roots from HROOT); 32 rows/block, acc[2][10] f32x4/thread;
//      exact max/expsum from registers; writes out directly.
// All GEMMs: C = A*B^T, bf16 operands, fp32 MFMA accumulate. Plain stores
// (R6: nontemporal breaks L2 write-combining on 4B scattered stores).

typedef unsigned short u16;
typedef short bf16x8 __attribute__((ext_vector_type(8)));
typedef float f32x4 __attribute__((ext_vector_type(4)));

#define NPER 1365
#define VDIM 600
#define VD2  602

#define MODE_PPA   0
#define MODE_UPROJ 1
#define MODE_ROOT  2

__device__ __forceinline__ float b2f(u16 h) {
  union { unsigned u; float f; } v; v.u = ((unsigned)h) << 16; return v.f;
}
__device__ __forceinline__ u16 f2bf(float f) {
  union { float f; unsigned u; } v; v.f = f;
  unsigned r = v.u + 0x7fff + ((v.u >> 16) & 1);
  return (u16)(r >> 16);
}
__device__ __forceinline__ float fsigm(float x) {
  return __fdividef(1.f, 1.f + __expf(-x));
}
__device__ __forceinline__ float ftanh(float x) {
  float e = __expf(-2.f * fabsf(x));
  float r = __fdividef(1.f - e, 1.f + e);
  return x < 0.f ? -r : r;
}

// chain-row ladder: r -> (off, pcs, start) for depths 1..5
__device__ __forceinline__ void ladder(int r, int& off, int& pcs, int& start) {
  if (r < 64)        { off = 0;    pcs = 0; start = 1;   }
  else if (r < 320)  { off = 64;   pcs = 2; start = 5;   }
  else if (r < 1344) { off = 320;  pcs = 4; start = 21;  }
  else if (r < 5440) { off = 1344; pcs = 6; start = 85;  }
  else               { off = 5440; pcs = 8; start = 341; }
}

// ---------------- pack kernel -----------------------------------------------
__global__ void k_pack(
    const float* __restrict__ Upar, const float* __restrict__ Whhp,
    const float* __restrict__ Usib, const float* __restrict__ Whhs,
    const float* __restrict__ z, const float* __restrict__ Wihp,
    const float* __restrict__ Wihs, const float* __restrict__ Wlab,
    const float* __restrict__ Wd, const float* __restrict__ Ww,
    const float* __restrict__ blab, const float* __restrict__ bd,
    const float* __restrict__ bw, const float* __restrict__ bihp,
    const float* __restrict__ bhhp, const float* __restrict__ bihs,
    const float* __restrict__ bhhs,
    u16* __restrict__ UPWHHP, u16* __restrict__ USWHHS, u16* __restrict__ ZBF,
    u16* __restrict__ WIHPT, u16* __restrict__ WIHST, u16* __restrict__ WEXT,
    float* __restrict__ BE, float* __restrict__ BP, float* __restrict__ BS) {
  int i = blockIdx.x * 256 + threadIdx.x;
  if (i < 327680) {
    int r = i >> 8, c = i & 255;
    UPWHHP[i] = f2bf(r < 256 ? Upar[(r << 8) | c] : Whhp[((r - 256) << 8) | c]);
    return;
  }
  i -= 327680;
  if (i < 327680) {
    int r = i >> 8, c = i & 255;
    USWHHS[i] = f2bf(r < 256 ? Usib[(r << 8) | c] : Whhs[((r - 256) << 8) | c]);
    return;
  }
  i -= 327680;
  if (i < 16384) { ZBF[i] = f2bf(z[i]); return; }
  i -= 16384;
  if (i < 614400) {  // W_ih_p [1024,600] -> [600,1024]; coalesced writes
    int r = i >> 10, c = i & 1023;
    WIHPT[i] = f2bf(Wihp[c * VDIM + r]); return;
  }
  i -= 614400;
  if (i < 614400) {
    int r = i >> 10, c = i & 1023;
    WIHST[i] = f2bf(Wihs[c * VDIM + r]); return;
  }
  i -= 614400;
  if (i < VD2 * 256) {
    int r = i >> 8, c = i & 255;
    float v = (r < VDIM) ? Wlab[r * 256 + c] : ((r == VDIM) ? Wd[c] : Ww[c]);
    WEXT[i] = f2bf(v); return;
  }
  i -= VD2 * 256;
  if (i < VD2) { BE[i] = (i < VDIM) ? blab[i] : ((i == VDIM) ? bd[0] : bw[0]); return; }
  i -= VD2;
  if (i < 1024) { BP[i] = bihp[i] + bhhp[i]; return; }
  i -= 1024;
  if (i < 1024) { BS[i] = bihs[i] + bhhs[i]; return; }
}

// ---------------- dual GEMM device fn: C = A*B^T, B=[1280,256] concat -------
// n0>=256 tiles -> gates (bf16 raw). n0<256 tiles by mode:
//  MODE_PPA  : ppa[(ppoff+row)*256+col] = bf16(acc)
//  MODE_UPROJ: uproj[row*256+col] = acc (fp32)
//  MODE_ROOT : hroot[row*256+col] = bf16(tanh(acc))   (compact 64x256)
__device__ __forceinline__ void dev_dual(
    int tile, int nx, const u16* __restrict__ A, const u16* __restrict__ B,
    int M, int mode, u16* __restrict__ ppa, int ppoff,
    float* __restrict__ uproj, u16* __restrict__ gates,
    u16* __restrict__ hroot) {
  static __shared__ __align__(16) u16 As[128 * 40];
  static __shared__ __align__(16) u16 Bs[128 * 40];
  const int m0 = (tile % nx) * 128, n0 = (tile / nx) * 128;
  const int tid = threadIdx.x;
  const int wave = tid >> 6, lane = tid & 63;
  const int quad = lane >> 4, lr = lane & 15;
  const int wm = (wave >> 1) * 64, wn = (wave & 1) * 64;
  const int srow = tid >> 2;
  const int sch = (tid & 3) << 3;

  f32x4 acc[4][4] = {};
  for (int t = 0; t < 8; ++t) {
    const int kk = t * 32;
    bf16x8 a0 = *(const bf16x8*)(A + (size_t)(m0 + srow) * 256 + kk + sch);
    bf16x8 a1 = *(const bf16x8*)(A + (size_t)(m0 + srow + 64) * 256 + kk + sch);
    bf16x8 b0 = *(const bf16x8*)(B + (size_t)(n0 + srow) * 256 + kk + sch);
    bf16x8 b1 = *(const bf16x8*)(B + (size_t)(n0 + srow + 64) * 256 + kk + sch);
    __syncthreads();
    *(bf16x8*)&As[srow * 40 + sch] = a0;
    *(bf16x8*)&As[(srow + 64) * 40 + sch] = a1;
    *(bf16x8*)&Bs[srow * 40 + sch] = b0;
    *(bf16x8*)&Bs[(srow + 64) * 40 + sch] = b1;
    __syncthreads();
    bf16x8 af[4], bfr[4];
#pragma unroll
    for (int tm = 0; tm < 4; ++tm)
      af[tm] = *(const bf16x8*)&As[(wm + tm * 16 + lr) * 40 + quad * 8];
#pragma unroll
    for (int tn = 0; tn < 4; ++tn)
      bfr[tn] = *(const bf16x8*)&Bs[(wn + tn * 16 + lr) * 40 + quad * 8];
#pragma unroll
    for (int tm = 0; tm < 4; ++tm)
#pragma unroll
      for (int tn = 0; tn < 4; ++tn)
        acc[tm][tn] = __builtin_amdgcn_mfma_f32_16x16x32_bf16(
            af[tm], bfr[tn], acc[tm][tn], 0, 0, 0);
  }

  const bool isg = (n0 >= 256);
#pragma unroll
  for (int tn = 0; tn < 4; ++tn) {
    int col = n0 + wn + tn * 16 + lr;
#pragma unroll
    for (int tm = 0; tm < 4; ++tm) {
#pragma unroll
      for (int r = 0; r < 4; ++r) {
        int row = m0 + wm + tm * 16 + quad * 4 + r;
        if (row >= M) continue;
        float v = acc[tm][tn][r];
        if (isg) {
          gates[(size_t)row * 1024 + (col - 256)] = f2bf(v);
        } else if (mode == MODE_PPA) {
          ppa[(size_t)(ppoff + row) * 256 + col] = f2bf(v);
        } else if (mode == MODE_UPROJ) {
          uproj[(size_t)row * 256 + col] = v;
        } else {  // MODE_ROOT
          hroot[(size_t)row * 256 + col] = f2bf(ftanh(v));
        }
      }
    }
  }
}

// ---------------- LSTM elementwise device fns (no LDS) ----------------------

__device__ __forceinline__ void dev_s0(int r, const u16* __restrict__ wihT,
    const float* __restrict__ bias, const int* __restrict__ feat,
    u16* __restrict__ h, u16* __restrict__ c) {
  int u = threadIdx.x;
  int off, pcs, start; ladder(r, off, pcs, start);
  int lg = r - off;
  int t = lg >> pcs, j = lg & ((1 << pcs) - 1);
  int lab = feat[t * NPER + start + 4 * j];
  const u16* wr = wihT + lab * 1024;
  float gi = b2f(wr[u])       + bias[u];
  float gg = b2f(wr[512 + u]) + bias[512 + u];
  float go = b2f(wr[768 + u]) + bias[768 + u];
  float cn = fsigm(gi) * ftanh(gg);
  float hn = fsigm(go) * ftanh(cn);
  h[(size_t)r * 256 + u] = f2bf(hn);
  c[(size_t)r * 256 + u] = f2bf(cn);
}

__device__ __forceinline__ void dev_lstm_sib(int r, int k,
    const u16* __restrict__ gates, const u16* __restrict__ wihT,
    const float* __restrict__ bias, const u16* __restrict__ c_in,
    const int* __restrict__ feat, u16* __restrict__ h, u16* __restrict__ c) {
  int u = threadIdx.x;
  int off, pcs, start; ladder(r, off, pcs, start);
  int lg = r - off;
  int t = lg >> pcs, j = lg & ((1 << pcs) - 1);
  int lab = feat[t * NPER + start + 4 * j + k];
  const u16* wr = wihT + lab * 1024;
  const u16* gr = gates + (size_t)r * 1024;
  float gi = b2f(wr[u])       + bias[u]       + b2f(gr[u]);
  float gf = b2f(wr[256 + u]) + bias[256 + u] + b2f(gr[256 + u]);
  float gg = b2f(wr[512 + u]) + bias[512 + u] + b2f(gr[512 + u]);
  float go = b2f(wr[768 + u]) + bias[768 + u] + b2f(gr[768 + u]);
  float cv = b2f(c_in[(size_t)r * 256 + u]);
  float cn = fsigm(gf) * cv + fsigm(gi) * ftanh(gg);
  float hn = fsigm(go) * ftanh(cn);
  h[(size_t)r * 256 + u] = f2bf(hn);
  c[(size_t)r * 256 + u] = f2bf(cn);
}

__device__ __forceinline__ void dev_lstm_par(int g,
    const u16* __restrict__ gates, const u16* __restrict__ wihT,
    const float* __restrict__ bias, const u16* __restrict__ c_in,
    const int* __restrict__ feat, u16* __restrict__ h, u16* __restrict__ c,
    int lsbits, int start) {
  int u = threadIdx.x;
  int t = g >> lsbits, p = g & ((1 << lsbits) - 1);
  int pr = lsbits ? ((t << (lsbits - 2)) | (p >> 2)) : g;
  int lab = feat[t * NPER + start + p];
  const u16* wr = wihT + lab * 1024;
  const u16* gr = gates + (size_t)pr * 1024;
  float gi = b2f(wr[u])       + bias[u]       + b2f(gr[u]);
  float gf = b2f(wr[256 + u]) + bias[256 + u] + b2f(gr[256 + u]);
  float gg = b2f(wr[512 + u]) + bias[512 + u] + b2f(gr[512 + u]);
  float go = b2f(wr[768 + u]) + bias[768 + u] + b2f(gr[768 + u]);
  float cv = c_in ? b2f(c_in[(size_t)pr * 256 + u]) : 0.f;
  float cn = fsigm(gf) * cv + fsigm(gi) * ftanh(gg);
  float hn = fsigm(go) * ftanh(cn);
  h[(size_t)g * 256 + u] = f2bf(hn);
  c[(size_t)g * 256 + u] = f2bf(cn);
}

// ---------------- launch kernels --------------------------------------------

__global__ __launch_bounds__(256) void k_s0(
    const u16* WIHST, const float* BS, const int* feat, u16* h, u16* c) {
  dev_s0(blockIdx.x, WIHST, BS, feat, h, c);
}

// GEMM || GEMM (shared 20KB LDS via dev_dual's function-local statics)
__global__ __launch_bounds__(256) void k_gg(
    int nA,
    const u16* Aa, const u16* Ba, int Ma, int nxa, int modea,
    u16* ppaa, int ppoffa, float* uproja, u16* gatesa, u16* hroota,
    const u16* Ab, const u16* Bb, int Mb, int nxb, int modeb,
    u16* ppab, int ppoffb, float* uprojb, u16* gatesb, u16* hrootb) {
  int b = blockIdx.x;
  if (b < nA)
    dev_dual(b, nxa, Aa, Ba, Ma, modea, ppaa, ppoffa, uproja, gatesa, hroota);
  else
    dev_dual(b - nA, nxb, Ab, Bb, Mb, modeb, ppab, ppoffb, uprojb, gatesb,
             hrootb);
}

// GEMM standalone
__global__ __launch_bounds__(256) void k_gemm(
    const u16* A, const u16* B, int M, int nx, int mode,
    u16* ppa, int ppoff, float* uproj, u16* gates, u16* hroot) {
  dev_dual(blockIdx.x, nx, A, B, M, mode, ppa, ppoff, uproj, gates, hroot);
}

// LSTM || LSTM (no LDS)
__global__ __launch_bounds__(256) void k_ll(
    int nP,
    const u16* gatesP, const u16* WIHPT, const float* BP, const u16* cpin,
    u16* hpout, u16* cpout, int lsbits, int startp,
    int kS, const u16* gatesS, const u16* WIHST, const float* BS,
    const u16* csin, u16* hsout, u16* csout, const int* feat) {
  int b = blockIdx.x;
  if (b < nP)
    dev_lstm_par(b, gatesP, WIHPT, BP, cpin, feat, hpout, cpout, lsbits,
                 startp);
  else
    dev_lstm_sib(b - nP, kS, gatesS, WIHST, BS, csin, feat, hsout, csout);
}

// LSTM standalone
__global__ __launch_bounds__(256) void k_plstm(
    const u16* gatesP, const u16* WIHPT, const float* BP, const u16* cpin,
    const int* feat, u16* hpout, u16* cpout, int lsbits, int start) {
  dev_lstm_par(blockIdx.x, gatesP, WIHPT, BP, cpin, feat, hpout, cpout,
               lsbits, start);
}

// ---------------- fused tail: assemble + logits GEMM + log-softmax ----------
// 32 rows/block (2730 blocks). A-staging computes hpred on the fly:
//   node = m0+row; t = node/NPER; q = node%NPER
//   q==0 -> HROOT[t]; else r = off + (t<<pcs) + (q-start)/4, s = (q-start)&3,
//   hpred = tanh(PPA[r] + (s ? UPROJ_s[r] : 0)).
// Wave w owns cols [w*160, w*160+160) as 10 col-tiles; acc[2][10]/thread.
__global__ __launch_bounds__(256, 2) void k_tail32(
    const u16* __restrict__ HROOT, const u16* __restrict__ PPA,
    const float* __restrict__ U1, const float* __restrict__ U2,
    const float* __restrict__ U3, const u16* __restrict__ B,
    const float* __restrict__ bias, float* __restrict__ out) {
  __shared__ __align__(16) u16 As[32 * 264];
  __shared__ float smax[32][4], ssum[32][4], slz[32];
  const int m0 = blockIdx.x * 32;
  const int tid = threadIdx.x;
  const int wave = tid >> 6, lane = tid & 63;
  const int quad = lane >> 4, lr = lane & 15;
  const int c0 = wave * 160;

  // staging with fused assemble (4 chunks of bf16x8 per thread)
#pragma unroll
  for (int cch = 0; cch < 4; ++cch) {
    int idx = cch * 256 + tid;
    int row = idx >> 5, ch = (idx & 31) << 3;
    int node = m0 + row;
    int t = node / NPER;
    int q = node - t * NPER;
    bf16x8 v8;
    if (q == 0) {
      v8 = *(const bf16x8*)(HROOT + (size_t)t * 256 + ch);
    } else {
      int off, pcs, start;
      if (q < 5)        { off = 0;    pcs = 0; start = 1;   }
      else if (q < 21)  { off = 64;   pcs = 2; start = 5;   }
      else if (q < 85)  { off = 320;  pcs = 4; start = 21;  }
      else if (q < 341) { off = 1344; pcs = 6; start = 85;  }
      else              { off = 5440; pcs = 8; start = 341; }
      int qq = q - start;
      int s = qq & 3, j = qq >> 2;
      int r = off + (t << pcs) + j;
      size_t ro = (size_t)r * 256 + ch;
      bf16x8 pp = *(const bf16x8*)(PPA + ro);
      const float* Us = (s == 1) ? U1 : ((s == 2) ? U2 : U3);
#pragma unroll
      for (int e = 0; e < 8; ++e) {
        float v = b2f((u16)pp[e]);
        if (s) v += Us[ro + e];
        v8[e] = (short)f2bf(ftanh(v));
      }
    }
    *(bf16x8*)&As[row * 264 + ch] = v8;
  }
  __syncthreads();

  f32x4 acc[2][10] = {};
#pragma unroll
  for (int t = 0; t < 8; ++t) {
    bf16x8 af[2], bfr[10];
#pragma unroll
    for (int tm = 0; tm < 2; ++tm)
      af[tm] = *(const bf16x8*)&As[(tm * 16 + lr) * 264 + t * 32 + quad * 8];
#pragma unroll
    for (int tn = 0; tn < 10; ++tn)
      bfr[tn] = *(const bf16x8*)(B + (size_t)(c0 + tn * 16 + lr) * 256 +
                                 t * 32 + quad * 8);
#pragma unroll
    for (int tm = 0; tm < 2; ++tm)
#pragma unroll
      for (int tn = 0; tn < 10; ++tn)
        acc[tm][tn] = __builtin_amdgcn_mfma_f32_16x16x32_bf16(
            af[tm], bfr[tn], acc[tm][tn], 0, 0, 0);
  }

  float bv[10]; bool val[10];
#pragma unroll
  for (int tn = 0; tn < 10; ++tn) {
    int col = c0 + tn * 16 + lr;
    val[tn] = (col < VDIM);
    bv[tn] = (col < VD2) ? bias[col] : 0.f;
  }

#pragma unroll
  for (int tm = 0; tm < 2; ++tm) {
#pragma unroll
    for (int r = 0; r < 4; ++r) {
      float mx = -1e30f;
#pragma unroll
      for (int tn = 0; tn < 10; ++tn)
        if (val[tn]) mx = fmaxf(mx, acc[tm][tn][r] + bv[tn]);
#pragma unroll
      for (int o = 1; o < 16; o <<= 1) mx = fmaxf(mx, __shfl_xor(mx, o, 64));
      if (lr == 0) smax[tm * 16 + quad * 4 + r][wave] = mx;
    }
  }
  __syncthreads();
#pragma unroll
  for (int tm = 0; tm < 2; ++tm) {
#pragma unroll
    for (int r = 0; r < 4; ++r) {
      int row = tm * 16 + quad * 4 + r;
      float fm = fmaxf(fmaxf(smax[row][0], smax[row][1]),
                       fmaxf(smax[row][2], smax[row][3]));
      float se = 0.f;
#pragma unroll
      for (int tn = 0; tn < 10; ++tn)
        if (val[tn]) se += __expf(acc[tm][tn][r] + bv[tn] - fm);
#pragma unroll
      for (int o = 1; o < 16; o <<= 1) se += __shfl_xor(se, o, 64);
      if (lr == 0) ssum[row][wave] = se;
    }
  }
  __syncthreads();
  if (tid < 32) {
    float fm = fmaxf(fmaxf(smax[tid][0], smax[tid][1]),
                     fmaxf(smax[tid][2], smax[tid][3]));
    slz[tid] = fm + __logf(ssum[tid][0] + ssum[tid][1] +
                           ssum[tid][2] + ssum[tid][3]);
  }
  __syncthreads();

#pragma unroll
  for (int tm = 0; tm < 2; ++tm) {
#pragma unroll
    for (int tn = 0; tn < 10; ++tn) {
      int col = c0 + tn * 16 + lr;
      if (col >= VD2) continue;
#pragma unroll
      for (int r = 0; r < 4; ++r) {
        int row = tm * 16 + quad * 4 + r;
        float v = acc[tm][tn][r] + bv[tn];
        out[(size_t)(m0 + row) * VD2 + col] =
            (col < VDIM) ? (v - slz[row]) : fsigm(v);
      }
    }
  }
}

// ---------------- host ------------------------------------------------------

extern "C" void kernel_launch(void* const* d_in, const int* in_sizes, int n_in,
                              void* d_out, int out_size, void* d_ws, size_t ws_size,
                              hipStream_t stream) {
  const float* z    = (const float*)d_in[0];
  const int*   feat = (const int*)d_in[1];
  const float* Wihp = (const float*)d_in[2];
  const float* Whhp = (const float*)d_in[3];
  const float* bihp = (const float*)d_in[4];
  const float* bhhp = (const float*)d_in[5];
  const float* Wihs = (const float*)d_in[6];
  const float* Whhs = (const float*)d_in[7];
  const float* bihs = (const float*)d_in[8];
  const float* bhhs = (const float*)d_in[9];
  const float* Upar = (const float*)d_in[10];
  const float* Usib = (const float*)d_in[11];
  const float* Wlab = (const float*)d_in[12];
  const float* blab = (const float*)d_in[13];
  const float* Wd   = (const float*)d_in[14];
  const float* bd   = (const float*)d_in[15];
  const float* Ww   = (const float*)d_in[16];
  const float* bw   = (const float*)d_in[17];
  float* out = (float*)d_out;

  char* w = (char*)d_ws;
  auto alloc = [&](size_t bytes) {
    char* p = w; w += (bytes + 255) & ~(size_t)255; return p;
  };
  u16*   UPWHHP = (u16*)alloc((size_t)1280 * 256 * 2);
  u16*   USWHHS = (u16*)alloc((size_t)1280 * 256 * 2);
  u16*   ZBF    = (u16*)alloc((size_t)128 * 256 * 2);   // rows 64..127 pad
  u16*   WIHPT  = (u16*)alloc((size_t)VDIM * 1024 * 2);
  u16*   WIHST  = (u16*)alloc((size_t)VDIM * 1024 * 2);
  u16*   WEXT   = (u16*)alloc((size_t)640 * 256 * 2);   // rows 602..639 pad
  float* BE     = (float*)alloc(VD2 * 4);
  float* BP     = (float*)alloc(1024 * 4);
  float* BS     = (float*)alloc(1024 * 4);
  const size_t CR = 21888;                              // 171*128 chain rows
  u16*   HSA[3], *CSA[3];
  for (int k = 0; k < 3; ++k) {
    HSA[k] = (u16*)alloc(CR * 256 * 2);
    CSA[k] = (u16*)alloc(CR * 256 * 2);
  }
  float* UPROJ[3];
  for (int k = 0; k < 3; ++k) UPROJ[k] = (float*)alloc(CR * 256 * 4);
  u16*   PPA   = (u16*)alloc(CR * 256 * 2);             // all chain rows
  u16*   HROOT = (u16*)alloc((size_t)64 * 256 * 2);
  const size_t SB = (size_t)16384 * 256 * 2;
  u16* HP[2] = {(u16*)alloc(SB), (u16*)alloc(SB)};
  u16* CP[2] = {(u16*)alloc(SB), (u16*)alloc(SB)};
  u16*   GATES  = (u16*)alloc(CR * 1024 * 2);
  u16*   GATESP = (u16*)alloc((size_t)4096 * 1024 * 2);

  // L1: pack
  k_pack<<<8037, 256, 0, stream>>>(Upar, Whhp, Usib, Whhs, z, Wihp, Wihs,
                                   Wlab, Wd, Ww, blab, bd, bw, bihp, bhhp,
                                   bihs, bhhs, UPWHHP, USWHHS, ZBF, WIHPT,
                                   WIHST, WEXT, BE, BP, BS);
  // L2: s0 (LDS-free, full occupancy)
  k_s0<<<21824, 256, 0, stream>>>(WIHST, BS, feat, HSA[0], CSA[0]);
  // L3: zdual (10) || sibdual1 (1710)
  k_gg<<<10 + 1710, 256, 0, stream>>>(
      10,
      ZBF, UPWHHP, 64, 1, MODE_ROOT, nullptr, 0, nullptr, GATESP, HROOT,
      HSA[0], USWHHS, 21824, 171, MODE_UPROJ, nullptr, 0, UPROJ[0], GATES,
      nullptr);
  // L4: plstm0 (64) || siblstm1 (21824)
  k_ll<<<64 + 21824, 256, 0, stream>>>(
      64, GATESP, WIHPT, BP, nullptr, HP[0], CP[0], 0, 0,
      1, GATES, WIHST, BS, CSA[0], HSA[1], CSA[1], feat);
  // L5: pdual1 (10) || sibdual2 (1710)
  k_gg<<<10 + 1710, 256, 0, stream>>>(
      10,
      HP[0], UPWHHP, 64, 1, MODE_PPA, PPA, 0, nullptr, GATESP, nullptr,
      HSA[1], USWHHS, 21824, 171, MODE_UPROJ, nullptr, 0, UPROJ[1], GATES,
      nullptr);
  // L6: plstm1 (256) || siblstm2 (21824)
  k_ll<<<256 + 21824, 256, 0, stream>>>(
      256, GATESP, WIHPT, BP, CP[0], HP[1], CP[1], 2, 1,
      2, GATES, WIHST, BS, CSA[1], HSA[2], CSA[2], feat);
  // L7: pdual2 (20) || sibdual3 (342, UPROJ only)
  k_gg<<<20 + 342, 256, 0, stream>>>(
      20,
      HP[1], UPWHHP, 256, 2, MODE_PPA, PPA, 64, nullptr, GATESP, nullptr,
      HSA[2], USWHHS, 21824, 171, MODE_UPROJ, nullptr, 0, UPROJ[2], nullptr,
      nullptr);
  // L8: plstm2 (1024)
  k_plstm<<<1024, 256, 0, stream>>>(GATESP, WIHPT, BP, CP[1], feat,
                                    HP[0], CP[0], 4, 5);
  // L9: pdual3 (80)
  k_gemm<<<80, 256, 0, stream>>>(HP[0], UPWHHP, 1024, 8, MODE_PPA,
                                 PPA, 320, nullptr, GATESP, nullptr);
  // L10: plstm3 (4096)
  k_plstm<<<4096, 256, 0, stream>>>(GATESP, WIHPT, BP, CP[0], feat,
                                    HP[1], CP[1], 6, 21);
  // L11: pdual4 (320)
  k_gemm<<<320, 256, 0, stream>>>(HP[1], UPWHHP, 4096, 32, MODE_PPA,
                                  PPA, 1344, nullptr, GATESP, nullptr);
  // L12: plstm4 (16384)
  k_plstm<<<16384, 256, 0, stream>>>(GATESP, WIHPT, BP, CP[1], feat,
                                     HP[0], CP[0], 8, 85);
  // L13: pdual5 (256, PPA only, ny=2)
  k_gemm<<<256, 256, 0, stream>>>(HP[0], UPWHHP, 16384, 128, MODE_PPA,
                                  PPA, 5440, nullptr, nullptr, nullptr);
  // L14: fused tail (assemble + GEMM + log-softmax), 32 rows/block
  k_tail32<<<2730, 256, 0, stream>>>(HROOT, PPA, UPROJ[0], UPROJ[1], UPROJ[2],
                                     WEXT, BE, out);

  (void)in_sizes; (void)n_in; (void)out_size; (void)ws_size;
}

// Round 10
// 619.967 us; speedup vs baseline: 1.3924x; 1.0604x over previous
//
#include <hip/hip_runtime.h>

// TreeLstmDecoder: B=64 trees, K=4, D=6, V=600, L=256, N_PER=1365, N=87360.
// 15-launch schedule. Mid (L1-L13) = R8's like-with-like merge schedule
// (GEMM||GEMM share the 20KB LDS; LSTM||LSTM are LDS-free) - measured ~450us.
// Assemble (hpred = tanh(PPA + UPROJ_s)) is a standalone LDS-free kernel,
// split by dependency: rows 0..5440 merged into L12 (|| plstm4), rows
// 5440..21824 after pdual5. Tail = R7's measured-149us HPRED-reading
// register-resident GEMM + log-softmax.
//  L1  k_pack
//  L2  k_s0                  (21824 sibling s=0 states, LDS-free)
//  L3  zdual || sibdual1     [GEMM: HPRED roots + gatesP ; UPROJ1+gates]
//  L4  plstm0 || siblstm1    [LSTM, LDS-free]
//  L5  pdual1 || sibdual2    [GEMM: PPA d1+gatesP ; UPROJ2+gates]
//  L6  plstm1 || siblstm2
//  L7  pdual2 || sibdual3    [GEMM: PPA d2+gatesP ; UPROJ3 only]
//  L8  plstm2   L9 pdual3   L10 plstm3   L11 pdual4
//  L12 plstm4 || assembleA (chain rows 0..5440, depths 1-4)
//  L13 pdual5 (PPA d5)
//  L14 assembleB (chain rows 5440..21824, depth 5)
//  L15 k_mm_tail (87360x602x256 GEMM + log-softmax, register-resident)
// All GEMMs: C = A*B^T, bf16 operands, fp32 MFMA accumulate. Plain stores
// (R6: nontemporal breaks L2 write-combining on 4B scattered stores).

typedef unsigned short u16;
typedef short bf16x8 __attribute__((ext_vector_type(8)));
typedef float f32x4 __attribute__((ext_vector_type(4)));

#define NPER 1365
#define VDIM 600
#define VD2  602

#define MODE_PPA   0
#define MODE_UPROJ 1
#define MODE_ROOT  2

__device__ __forceinline__ float b2f(u16 h) {
  union { unsigned u; float f; } v; v.u = ((unsigned)h) << 16; return v.f;
}
__device__ __forceinline__ u16 f2bf(float f) {
  union { float f; unsigned u; } v; v.f = f;
  unsigned r = v.u + 0x7fff + ((v.u >> 16) & 1);
  return (u16)(r >> 16);
}
__device__ __forceinline__ float fsigm(float x) {
  return __fdividef(1.f, 1.f + __expf(-x));
}
__device__ __forceinline__ float ftanh(float x) {
  float e = __expf(-2.f * fabsf(x));
  float r = __fdividef(1.f - e, 1.f + e);
  return x < 0.f ? -r : r;
}

// chain-row ladder: r -> (off, pcs, start) for depths 1..5
__device__ __forceinline__ void ladder(int r, int& off, int& pcs, int& start) {
  if (r < 64)        { off = 0;    pcs = 0; start = 1;   }
  else if (r < 320)  { off = 64;   pcs = 2; start = 5;   }
  else if (r < 1344) { off = 320;  pcs = 4; start = 21;  }
  else if (r < 5440) { off = 1344; pcs = 6; start = 85;  }
  else               { off = 5440; pcs = 8; start = 341; }
}

// ---------------- pack kernel -----------------------------------------------
__global__ void k_pack(
    const float* __restrict__ Upar, const float* __restrict__ Whhp,
    const float* __restrict__ Usib, const float* __restrict__ Whhs,
    const float* __restrict__ z, const float* __restrict__ Wihp,
    const float* __restrict__ Wihs, const float* __restrict__ Wlab,
    const float* __restrict__ Wd, const float* __restrict__ Ww,
    const float* __restrict__ blab, const float* __restrict__ bd,
    const float* __restrict__ bw, const float* __restrict__ bihp,
    const float* __restrict__ bhhp, const float* __restrict__ bihs,
    const float* __restrict__ bhhs,
    u16* __restrict__ UPWHHP, u16* __restrict__ USWHHS, u16* __restrict__ ZBF,
    u16* __restrict__ WIHPT, u16* __restrict__ WIHST, u16* __restrict__ WEXT,
    float* __restrict__ BE, float* __restrict__ BP, float* __restrict__ BS) {
  int i = blockIdx.x * 256 + threadIdx.x;
  if (i < 327680) {
    int r = i >> 8, c = i & 255;
    UPWHHP[i] = f2bf(r < 256 ? Upar[(r << 8) | c] : Whhp[((r - 256) << 8) | c]);
    return;
  }
  i -= 327680;
  if (i < 327680) {
    int r = i >> 8, c = i & 255;
    USWHHS[i] = f2bf(r < 256 ? Usib[(r << 8) | c] : Whhs[((r - 256) << 8) | c]);
    return;
  }
  i -= 327680;
  if (i < 16384) { ZBF[i] = f2bf(z[i]); return; }
  i -= 16384;
  if (i < 614400) {  // W_ih_p [1024,600] -> [600,1024]; coalesced writes
    int r = i >> 10, c = i & 1023;
    WIHPT[i] = f2bf(Wihp[c * VDIM + r]); return;
  }
  i -= 614400;
  if (i < 614400) {
    int r = i >> 10, c = i & 1023;
    WIHST[i] = f2bf(Wihs[c * VDIM + r]); return;
  }
  i -= 614400;
  if (i < VD2 * 256) {
    int r = i >> 8, c = i & 255;
    float v = (r < VDIM) ? Wlab[r * 256 + c] : ((r == VDIM) ? Wd[c] : Ww[c]);
    WEXT[i] = f2bf(v); return;
  }
  i -= VD2 * 256;
  if (i < VD2) { BE[i] = (i < VDIM) ? blab[i] : ((i == VDIM) ? bd[0] : bw[0]); return; }
  i -= VD2;
  if (i < 1024) { BP[i] = bihp[i] + bhhp[i]; return; }
  i -= 1024;
  if (i < 1024) { BS[i] = bihs[i] + bhhs[i]; return; }
}

// ---------------- dual GEMM device fn: C = A*B^T, B=[1280,256] concat -------
// n0>=256 tiles -> gates (bf16 raw). n0<256 tiles by mode:
//  MODE_PPA  : ppa[(ppoff+row)*256+col] = bf16(acc)
//  MODE_UPROJ: uproj[row*256+col] = acc (fp32)
//  MODE_ROOT : hpred[row*NPER*256+col] = bf16(tanh(acc))  (root node rows)
__device__ __forceinline__ void dev_dual(
    int tile, int nx, const u16* __restrict__ A, const u16* __restrict__ B,
    int M, int mode, u16* __restrict__ ppa, int ppoff,
    float* __restrict__ uproj, u16* __restrict__ gates,
    u16* __restrict__ hpred) {
  static __shared__ __align__(16) u16 As[128 * 40];
  static __shared__ __align__(16) u16 Bs[128 * 40];
  const int m0 = (tile % nx) * 128, n0 = (tile / nx) * 128;
  const int tid = threadIdx.x;
  const int wave = tid >> 6, lane = tid & 63;
  const int quad = lane >> 4, lr = lane & 15;
  const int wm = (wave >> 1) * 64, wn = (wave & 1) * 64;
  const int srow = tid >> 2;
  const int sch = (tid & 3) << 3;

  f32x4 acc[4][4] = {};
  for (int t = 0; t < 8; ++t) {
    const int kk = t * 32;
    bf16x8 a0 = *(const bf16x8*)(A + (size_t)(m0 + srow) * 256 + kk + sch);
    bf16x8 a1 = *(const bf16x8*)(A + (size_t)(m0 + srow + 64) * 256 + kk + sch);
    bf16x8 b0 = *(const bf16x8*)(B + (size_t)(n0 + srow) * 256 + kk + sch);
    bf16x8 b1 = *(const bf16x8*)(B + (size_t)(n0 + srow + 64) * 256 + kk + sch);
    __syncthreads();
    *(bf16x8*)&As[srow * 40 + sch] = a0;
    *(bf16x8*)&As[(srow + 64) * 40 + sch] = a1;
    *(bf16x8*)&Bs[srow * 40 + sch] = b0;
    *(bf16x8*)&Bs[(srow + 64) * 40 + sch] = b1;
    __syncthreads();
    bf16x8 af[4], bfr[4];
#pragma unroll
    for (int tm = 0; tm < 4; ++tm)
      af[tm] = *(const bf16x8*)&As[(wm + tm * 16 + lr) * 40 + quad * 8];
#pragma unroll
    for (int tn = 0; tn < 4; ++tn)
      bfr[tn] = *(const bf16x8*)&Bs[(wn + tn * 16 + lr) * 40 + quad * 8];
#pragma unroll
    for (int tm = 0; tm < 4; ++tm)
#pragma unroll
      for (int tn = 0; tn < 4; ++tn)
        acc[tm][tn] = __builtin_amdgcn_mfma_f32_16x16x32_bf16(
            af[tm], bfr[tn], acc[tm][tn], 0, 0, 0);
  }

  const bool isg = (n0 >= 256);
#pragma unroll
  for (int tn = 0; tn < 4; ++tn) {
    int col = n0 + wn + tn * 16 + lr;
#pragma unroll
    for (int tm = 0; tm < 4; ++tm) {
#pragma unroll
      for (int r = 0; r < 4; ++r) {
        int row = m0 + wm + tm * 16 + quad * 4 + r;
        if (row >= M) continue;
        float v = acc[tm][tn][r];
        if (isg) {
          gates[(size_t)row * 1024 + (col - 256)] = f2bf(v);
        } else if (mode == MODE_PPA) {
          ppa[(size_t)(ppoff + row) * 256 + col] = f2bf(v);
        } else if (mode == MODE_UPROJ) {
          uproj[(size_t)row * 256 + col] = v;
        } else {  // MODE_ROOT: node index = row * NPER
          hpred[(size_t)row * NPER * 256 + col] = f2bf(ftanh(v));
        }
      }
    }
  }
}

// ---------------- LSTM / assemble elementwise device fns (no LDS) -----------

__device__ __forceinline__ void dev_s0(int r, const u16* __restrict__ wihT,
    const float* __restrict__ bias, const int* __restrict__ feat,
    u16* __restrict__ h, u16* __restrict__ c) {
  int u = threadIdx.x;
  int off, pcs, start; ladder(r, off, pcs, start);
  int lg = r - off;
  int t = lg >> pcs, j = lg & ((1 << pcs) - 1);
  int lab = feat[t * NPER + start + 4 * j];
  const u16* wr = wihT + lab * 1024;
  float gi = b2f(wr[u])       + bias[u];
  float gg = b2f(wr[512 + u]) + bias[512 + u];
  float go = b2f(wr[768 + u]) + bias[768 + u];
  float cn = fsigm(gi) * ftanh(gg);
  float hn = fsigm(go) * ftanh(cn);
  h[(size_t)r * 256 + u] = f2bf(hn);
  c[(size_t)r * 256 + u] = f2bf(cn);
}

__device__ __forceinline__ void dev_lstm_sib(int r, int k,
    const u16* __restrict__ gates, const u16* __restrict__ wihT,
    const float* __restrict__ bias, const u16* __restrict__ c_in,
    const int* __restrict__ feat, u16* __restrict__ h, u16* __restrict__ c) {
  int u = threadIdx.x;
  int off, pcs, start; ladder(r, off, pcs, start);
  int lg = r - off;
  int t = lg >> pcs, j = lg & ((1 << pcs) - 1);
  int lab = feat[t * NPER + start + 4 * j + k];
  const u16* wr = wihT + lab * 1024;
  const u16* gr = gates + (size_t)r * 1024;
  float gi = b2f(wr[u])       + bias[u]       + b2f(gr[u]);
  float gf = b2f(wr[256 + u]) + bias[256 + u] + b2f(gr[256 + u]);
  float gg = b2f(wr[512 + u]) + bias[512 + u] + b2f(gr[512 + u]);
  float go = b2f(wr[768 + u]) + bias[768 + u] + b2f(gr[768 + u]);
  float cv = b2f(c_in[(size_t)r * 256 + u]);
  float cn = fsigm(gf) * cv + fsigm(gi) * ftanh(gg);
  float hn = fsigm(go) * ftanh(cn);
  h[(size_t)r * 256 + u] = f2bf(hn);
  c[(size_t)r * 256 + u] = f2bf(cn);
}

__device__ __forceinline__ void dev_lstm_par(int g,
    const u16* __restrict__ gates, const u16* __restrict__ wihT,
    const float* __restrict__ bias, const u16* __restrict__ c_in,
    const int* __restrict__ feat, u16* __restrict__ h, u16* __restrict__ c,
    int lsbits, int start) {
  int u = threadIdx.x;
  int t = g >> lsbits, p = g & ((1 << lsbits) - 1);
  int pr = lsbits ? ((t << (lsbits - 2)) | (p >> 2)) : g;
  int lab = feat[t * NPER + start + p];
  const u16* wr = wihT + lab * 1024;
  const u16* gr = gates + (size_t)pr * 1024;
  float gi = b2f(wr[u])       + bias[u]       + b2f(gr[u]);
  float gf = b2f(wr[256 + u]) + bias[256 + u] + b2f(gr[256 + u]);
  float gg = b2f(wr[512 + u]) + bias[512 + u] + b2f(gr[512 + u]);
  float go = b2f(wr[768 + u]) + bias[768 + u] + b2f(gr[768 + u]);
  float cv = c_in ? b2f(c_in[(size_t)pr * 256 + u]) : 0.f;
  float cn = fsigm(gf) * cv + fsigm(gi) * ftanh(gg);
  float hn = fsigm(go) * ftanh(cn);
  h[(size_t)g * 256 + u] = f2bf(hn);
  c[(size_t)g * 256 + u] = f2bf(cn);
}

// assemble chain row r: hpred rows s=0..3 = tanh(PPA[r] (+ U_s[r]))
__device__ __forceinline__ void dev_assemble(int r,
    const u16* __restrict__ PPA, const float* __restrict__ U1,
    const float* __restrict__ U2, const float* __restrict__ U3,
    u16* __restrict__ HPRED) {
  int u = threadIdx.x;
  int off, pcs, start; ladder(r, off, pcs, start);
  int lg = r - off;
  int t = lg >> pcs, j = lg & ((1 << pcs) - 1);
  size_t base = ((size_t)(t * NPER + start + 4 * j)) * 256 + u;
  size_t ro = (size_t)r * 256 + u;
  float pp = b2f(PPA[ro]);
  HPRED[base]       = f2bf(ftanh(pp));
  HPRED[base + 256] = f2bf(ftanh(pp + U1[ro]));
  HPRED[base + 512] = f2bf(ftanh(pp + U2[ro]));
  HPRED[base + 768] = f2bf(ftanh(pp + U3[ro]));
}

// ---------------- launch kernels --------------------------------------------

__global__ __launch_bounds__(256) void k_s0(
    const u16* WIHST, const float* BS, const int* feat, u16* h, u16* c) {
  dev_s0(blockIdx.x, WIHST, BS, feat, h, c);
}

// GEMM || GEMM (shared 20KB LDS via dev_dual's function-local statics)
__global__ __launch_bounds__(256) void k_gg(
    int nA,
    const u16* Aa, const u16* Ba, int Ma, int nxa, int modea,
    u16* ppaa, int ppoffa, float* uproja, u16* gatesa, u16* hpreda,
    const u16* Ab, const u16* Bb, int Mb, int nxb, int modeb,
    u16* ppab, int ppoffb, float* uprojb, u16* gatesb, u16* hpredb) {
  int b = blockIdx.x;
  if (b < nA)
    dev_dual(b, nxa, Aa, Ba, Ma, modea, ppaa, ppoffa, uproja, gatesa, hpreda);
  else
    dev_dual(b - nA, nxb, Ab, Bb, Mb, modeb, ppab, ppoffb, uprojb, gatesb,
             hpredb);
}

// GEMM standalone
__global__ __launch_bounds__(256) void k_gemm(
    const u16* A, const u16* B, int M, int nx, int mode,
    u16* ppa, int ppoff, float* uproj, u16* gates, u16* hpred) {
  dev_dual(blockIdx.x, nx, A, B, M, mode, ppa, ppoff, uproj, gates, hpred);
}

// LSTM || LSTM (no LDS)
__global__ __launch_bounds__(256) void k_ll(
    int nP,
    const u16* gatesP, const u16* WIHPT, const float* BP, const u16* cpin,
    u16* hpout, u16* cpout, int lsbits, int startp,
    int kS, const u16* gatesS, const u16* WIHST, const float* BS,
    const u16* csin, u16* hsout, u16* csout, const int* feat) {
  int b = blockIdx.x;
  if (b < nP)
    dev_lstm_par(b, gatesP, WIHPT, BP, cpin, feat, hpout, cpout, lsbits,
                 startp);
  else
    dev_lstm_sib(b - nP, kS, gatesS, WIHST, BS, csin, feat, hsout, csout);
}

// LSTM standalone
__global__ __launch_bounds__(256) void k_plstm(
    const u16* gatesP, const u16* WIHPT, const float* BP, const u16* cpin,
    const int* feat, u16* hpout, u16* cpout, int lsbits, int start) {
  dev_lstm_par(blockIdx.x, gatesP, WIHPT, BP, cpin, feat, hpout, cpout,
               lsbits, start);
}

// L12: plstm4 (16384) || assembleA (chain rows 0..5440) — both LDS-free
__global__ __launch_bounds__(256) void k_plstm_asm(
    const u16* gatesP, const u16* WIHPT, const float* BP, const u16* cpin,
    const int* feat, u16* hpout, u16* cpout,
    const u16* PPA, const float* U1, const float* U2, const float* U3,
    u16* HPRED) {
  int b = blockIdx.x;
  if (b < 16384)
    dev_lstm_par(b, gatesP, WIHPT, BP, cpin, feat, hpout, cpout, 8, 85);
  else
    dev_assemble(b - 16384, PPA, U1, U2, U3, HPRED);
}

// L14: assembleB (chain rows 5440..21824)
__global__ __launch_bounds__(256) void k_assemble(
    const u16* PPA, const float* U1, const float* U2, const float* U3,
    u16* HPRED) {
  dev_assemble(5440 + blockIdx.x, PPA, U1, U2, U3, HPRED);
}

// ---------------- fused tail: logits GEMM + log-softmax (R7, 149us) ---------
__global__ __launch_bounds__(256, 2) void k_mm_tail(
    const u16* __restrict__ A, const u16* __restrict__ B,
    const float* __restrict__ bias, float* __restrict__ out) {
  __shared__ __align__(16) u16 As[32 * 264];
  __shared__ float smax[32][4], ssum[32][4], slz[32];
  const int m0 = blockIdx.x * 32;
  const int tid = threadIdx.x;
  const int wave = tid >> 6, lane = tid & 63;
  const int quad = lane >> 4, lr = lane & 15;
  const int c0 = wave * 160;

#pragma unroll
  for (int c = 0; c < 4; ++c) {
    int idx = c * 256 + tid;
    int row = idx >> 5, ch = (idx & 31) << 3;
    *(bf16x8*)&As[row * 264 + ch] =
        *(const bf16x8*)(A + (size_t)(m0 + row) * 256 + ch);
  }
  __syncthreads();

  f32x4 acc[2][10] = {};
#pragma unroll
  for (int t = 0; t < 8; ++t) {
    bf16x8 af[2], bfr[10];
#pragma unroll
    for (int tm = 0; tm < 2; ++tm)
      af[tm] = *(const bf16x8*)&As[(tm * 16 + lr) * 264 + t * 32 + quad * 8];
#pragma unroll
    for (int tn = 0; tn < 10; ++tn)
      bfr[tn] = *(const bf16x8*)(B + (size_t)(c0 + tn * 16 + lr) * 256 +
                                 t * 32 + quad * 8);
#pragma unroll
    for (int tm = 0; tm < 2; ++tm)
#pragma unroll
      for (int tn = 0; tn < 10; ++tn)
        acc[tm][tn] = __builtin_amdgcn_mfma_f32_16x16x32_bf16(
            af[tm], bfr[tn], acc[tm][tn], 0, 0, 0);
  }

  float bv[10]; bool val[10];
#pragma unroll
  for (int tn = 0; tn < 10; ++tn) {
    int col = c0 + tn * 16 + lr;
    val[tn] = (col < VDIM);
    bv[tn] = (col < VD2) ? bias[col] : 0.f;
  }

#pragma unroll
  for (int tm = 0; tm < 2; ++tm) {
#pragma unroll
    for (int r = 0; r < 4; ++r) {
      float mx = -1e30f;
#pragma unroll
      for (int tn = 0; tn < 10; ++tn)
        if (val[tn]) mx = fmaxf(mx, acc[tm][tn][r] + bv[tn]);
#pragma unroll
      for (int o = 1; o < 16; o <<= 1) mx = fmaxf(mx, __shfl_xor(mx, o, 64));
      if (lr == 0) smax[tm * 16 + quad * 4 + r][wave] = mx;
    }
  }
  __syncthreads();
#pragma unroll
  for (int tm = 0; tm < 2; ++tm) {
#pragma unroll
    for (int r = 0; r < 4; ++r) {
      int row = tm * 16 + quad * 4 + r;
      float fm = fmaxf(fmaxf(smax[row][0], smax[row][1]),
                       fmaxf(smax[row][2], smax[row][3]));
      float se = 0.f;
#pragma unroll
      for (int tn = 0; tn < 10; ++tn)
        if (val[tn]) se += __expf(acc[tm][tn][r] + bv[tn] - fm);
#pragma unroll
      for (int o = 1; o < 16; o <<= 1) se += __shfl_xor(se, o, 64);
      if (lr == 0) ssum[row][wave] = se;
    }
  }
  __syncthreads();
  if (tid < 32) {
    float fm = fmaxf(fmaxf(smax[tid][0], smax[tid][1]),
                     fmaxf(smax[tid][2], smax[tid][3]));
    slz[tid] = fm + __logf(ssum[tid][0] + ssum[tid][1] +
                           ssum[tid][2] + ssum[tid][3]);
  }
  __syncthreads();

#pragma unroll
  for (int tm = 0; tm < 2; ++tm) {
#pragma unroll
    for (int tn = 0; tn < 10; ++tn) {
      int col = c0 + tn * 16 + lr;
      if (col >= VD2) continue;
#pragma unroll
      for (int r = 0; r < 4; ++r) {
        int row = tm * 16 + quad * 4 + r;
        float v = acc[tm][tn][r] + bv[tn];
        out[(size_t)(m0 + row) * VD2 + col] =
            (col < VDIM) ? (v - slz[row]) : fsigm(v);
      }
    }
  }
}

// ---------------- host ------------------------------------------------------

extern "C" void kernel_launch(void* const* d_in, const int* in_sizes, int n_in,
                              void* d_out, int out_size, void* d_ws, size_t ws_size,
                              hipStream_t stream) {
  const float* z    = (const float*)d_in[0];
  const int*   feat = (const int*)d_in[1];
  const float* Wihp = (const float*)d_in[2];
  const float* Whhp = (const float*)d_in[3];
  const float* bihp = (const float*)d_in[4];
  const float* bhhp = (const float*)d_in[5];
  const float* Wihs = (const float*)d_in[6];
  const float* Whhs = (const float*)d_in[7];
  const float* bihs = (const float*)d_in[8];
  const float* bhhs = (const float*)d_in[9];
  const float* Upar = (const float*)d_in[10];
  const float* Usib = (const float*)d_in[11];
  const float* Wlab = (const float*)d_in[12];
  const float* blab = (const float*)d_in[13];
  const float* Wd   = (const float*)d_in[14];
  const float* bd   = (const float*)d_in[15];
  const float* Ww   = (const float*)d_in[16];
  const float* bw   = (const float*)d_in[17];
  float* out = (float*)d_out;

  char* w = (char*)d_ws;
  auto alloc = [&](size_t bytes) {
    char* p = w; w += (bytes + 255) & ~(size_t)255; return p;
  };
  u16*   UPWHHP = (u16*)alloc((size_t)1280 * 256 * 2);
  u16*   USWHHS = (u16*)alloc((size_t)1280 * 256 * 2);
  u16*   ZBF    = (u16*)alloc((size_t)128 * 256 * 2);   // rows 64..127 pad
  u16*   WIHPT  = (u16*)alloc((size_t)VDIM * 1024 * 2);
  u16*   WIHST  = (u16*)alloc((size_t)VDIM * 1024 * 2);
  u16*   WEXT   = (u16*)alloc((size_t)640 * 256 * 2);   // rows 602..639 pad
  float* BE     = (float*)alloc(VD2 * 4);
  float* BP     = (float*)alloc(1024 * 4);
  float* BS     = (float*)alloc(1024 * 4);
  const size_t CR = 21888;                              // 171*128 chain rows
  u16*   HSA[3], *CSA[3];
  for (int k = 0; k < 3; ++k) {
    HSA[k] = (u16*)alloc(CR * 256 * 2);
    CSA[k] = (u16*)alloc(CR * 256 * 2);
  }
  float* UPROJ[3];
  for (int k = 0; k < 3; ++k) UPROJ[k] = (float*)alloc(CR * 256 * 4);
  u16*   PPA   = (u16*)alloc(CR * 256 * 2);             // all chain rows
  const size_t SB = (size_t)16384 * 256 * 2;
  u16* HP[2] = {(u16*)alloc(SB), (u16*)alloc(SB)};
  u16* CP[2] = {(u16*)alloc(SB), (u16*)alloc(SB)};
  u16*   GATES  = (u16*)alloc(CR * 1024 * 2);
  u16*   GATESP = (u16*)alloc((size_t)4096 * 1024 * 2);
  u16*   HPRED  = (u16*)alloc((size_t)87424 * 256 * 2); // node-ordered, +pad

  // L1: pack
  k_pack<<<8037, 256, 0, stream>>>(Upar, Whhp, Usib, Whhs, z, Wihp, Wihs,
                                   Wlab, Wd, Ww, blab, bd, bw, bihp, bhhp,
                                   bihs, bhhs, UPWHHP, USWHHS, ZBF, WIHPT,
                                   WIHST, WEXT, BE, BP, BS);
  // L2: s0 (LDS-free, full occupancy)
  k_s0<<<21824, 256, 0, stream>>>(WIHST, BS, feat, HSA[0], CSA[0]);
  // L3: zdual (10, roots -> HPRED) || sibdual1 (1710)
  k_gg<<<10 + 1710, 256, 0, stream>>>(
      10,
      ZBF, UPWHHP, 64, 1, MODE_ROOT, nullptr, 0, nullptr, GATESP, HPRED,
      HSA[0], USWHHS, 21824, 171, MODE_UPROJ, nullptr, 0, UPROJ[0], GATES,
      nullptr);
  // L4: plstm0 (64) || siblstm1 (21824)
  k_ll<<<64 + 21824, 256, 0, stream>>>(
      64, GATESP, WIHPT, BP, nullptr, HP[0], CP[0], 0, 0,
      1, GATES, WIHST, BS, CSA[0], HSA[1], CSA[1], feat);
  // L5: pdual1 (10) || sibdual2 (1710)
  k_gg<<<10 + 1710, 256, 0, stream>>>(
      10,
      HP[0], UPWHHP, 64, 1, MODE_PPA, PPA, 0, nullptr, GATESP, nullptr,
      HSA[1], USWHHS, 21824, 171, MODE_UPROJ, nullptr, 0, UPROJ[1], GATES,
      nullptr);
  // L6: plstm1 (256) || siblstm2 (21824)
  k_ll<<<256 + 21824, 256, 0, stream>>>(
      256, GATESP, WIHPT, BP, CP[0], HP[1], CP[1], 2, 1,
      2, GATES, WIHST, BS, CSA[1], HSA[2], CSA[2], feat);
  // L7: pdual2 (20) || sibdual3 (342, UPROJ only)
  k_gg<<<20 + 342, 256, 0, stream>>>(
      20,
      HP[1], UPWHHP, 256, 2, MODE_PPA, PPA, 64, nullptr, GATESP, nullptr,
      HSA[2], USWHHS, 21824, 171, MODE_UPROJ, nullptr, 0, UPROJ[2], nullptr,
      nullptr);
  // L8: plstm2 (1024)
  k_plstm<<<1024, 256, 0, stream>>>(GATESP, WIHPT, BP, CP[1], feat,
                                    HP[0], CP[0], 4, 5);
  // L9: pdual3 (80)
  k_gemm<<<80, 256, 0, stream>>>(HP[0], UPWHHP, 1024, 8, MODE_PPA,
                                 PPA, 320, nullptr, GATESP, nullptr);
  // L10: plstm3 (4096)
  k_plstm<<<4096, 256, 0, stream>>>(GATESP, WIHPT, BP, CP[0], feat,
                                    HP[1], CP[1], 6, 21);
  // L11: pdual4 (320)
  k_gemm<<<320, 256, 0, stream>>>(HP[1], UPWHHP, 4096, 32, MODE_PPA,
                                  PPA, 1344, nullptr, GATESP, nullptr);
  // L12: plstm4 (16384) || assembleA (5440: chain rows 0..5440)
  k_plstm_asm<<<16384 + 5440, 256, 0, stream>>>(
      GATESP, WIHPT, BP, CP[1], feat, HP[0], CP[0],
      PPA, UPROJ[0], UPROJ[1], UPROJ[2], HPRED);
  // L13: pdual5 (256, PPA only, ny=2)
  k_gemm<<<256, 256, 0, stream>>>(HP[0], UPWHHP, 16384, 128, MODE_PPA,
                                  PPA, 5440, nullptr, nullptr, nullptr);
  // L14: assembleB (16384: chain rows 5440..21824)
  k_assemble<<<16384, 256, 0, stream>>>(PPA, UPROJ[0], UPROJ[1], UPROJ[2],
                                        HPRED);
  // L15: fused tail (GEMM + log-softmax, HPRED reader)
  k_mm_tail<<<2730, 256, 0, stream>>>(HPRED, WEXT, BE, out);

  (void)in_sizes; (void)n_in; (void)out_size; (void)ws_size;
}